// Round 1
// baseline (661.198 us; speedup 1.0000x reference)
//
#include <hip/hip_runtime.h>

#define BB 8
#define NN 2048
#define DD 64
constexpr float EPS = 0.1f;
constexpr int ITERS = 10;

// ---------------------------------------------------------------- row_sq
// sq[b,n] = sum_d x[b,n,d]^2 ; one wave per row (D=64 -> lane==d)
__global__ __launch_bounds__(256) void row_sq(const float* __restrict__ X,
                                              float* __restrict__ sq) {
    const int row  = blockIdx.x * 4 + (threadIdx.x >> 6);
    const int lane = threadIdx.x & 63;
    float x = X[(size_t)row * DD + lane];
    float s = x * x;
    #pragma unroll
    for (int off = 32; off > 0; off >>= 1) s += __shfl_down(s, off);
    if (lane == 0) sq[row] = s;
}

// ---------------------------------------------------------------- batch_stats
// Closed-form C_mean: mean(C) = 2*sum(sq)/N - 2*|sum_n x|^2/N^2
// scale[b] = -1/(C_mean * eps)  so  log_K = scale * C
__global__ __launch_bounds__(256) void batch_stats(const float* __restrict__ X,
                                                   const float* __restrict__ sq,
                                                   float* __restrict__ scale) {
    __shared__ float col[4][64];
    __shared__ float tot[256];
    const int b = blockIdx.x, t = threadIdx.x;
    const int w = t >> 6, lane = t & 63;
    const float* Xb = X + (size_t)b * NN * DD;
    float cs = 0.f;                       // column (per-d) sum over n
    for (int n = w; n < NN; n += 4) cs += Xb[n * DD + lane];
    col[w][lane] = cs;
    float tt = 0.f;                       // total sum of sq
    for (int i = t; i < NN; i += 256) tt += sq[b * NN + i];
    tot[t] = tt;
    __syncthreads();
    for (int s = 128; s > 0; s >>= 1) {
        if (t < s) tot[t] += tot[t + s];
        __syncthreads();
    }
    if (t < 64) {
        float sd = col[0][t] + col[1][t] + col[2][t] + col[3][t];
        float s2 = sd * sd;
        #pragma unroll
        for (int off = 32; off > 0; off >>= 1) s2 += __shfl_down(s2, off);
        if (t == 0) {
            float T = tot[0];
            float cmean = 2.0f * T / (float)NN
                        - 2.0f * s2 / ((float)NN * (float)NN) + 1e-8f;
            scale[b] = -1.0f / (cmean * EPS);
        }
    }
}

// ---------------------------------------------------------------- init
__global__ void init_vw(float* __restrict__ v, float* __restrict__ outW) {
    const int i = blockIdx.x * 256 + threadIdx.x;
    v[i]    = 1.0f;
    outW[i] = 1.0f / (float)NN;
}

// ---------------------------------------------------------------- build_K
// K[b,n,m] = exp(scale[b] * (sq[n] + sq[m] - 2 * x_n . x_m))
// 64x64 output tile per block, K-dim = D = 64 fully in LDS (transposed layout
// so the inner loop is 2x ds_read_b128 + 16 FMA per k).
__global__ __launch_bounds__(256) void build_K(const float* __restrict__ X,
                                               const float* __restrict__ sq,
                                               const float* __restrict__ scale,
                                               float* __restrict__ K) {
    __shared__ float XnT[64][68];   // [k][n-row], pitch 68 for b128 alignment
    __shared__ float XmT[64][68];   // [k][m-row]
    const int b = blockIdx.z, nt = blockIdx.y, mt = blockIdx.x;
    const int t = threadIdx.x;
    const float* Xb = X + (size_t)b * NN * DD;
    #pragma unroll
    for (int i = 0; i < 4; ++i) {
        int f   = t + i * 256;        // 0..1023
        int row = f >> 4;             // 0..63
        int c4  = (f & 15) << 2;      // 0..60
        float4 a = *(const float4*)(Xb + (size_t)(nt * 64 + row) * DD + c4);
        XnT[c4 + 0][row] = a.x; XnT[c4 + 1][row] = a.y;
        XnT[c4 + 2][row] = a.z; XnT[c4 + 3][row] = a.w;
        float4 bb = *(const float4*)(Xb + (size_t)(mt * 64 + row) * DD + c4);
        XmT[c4 + 0][row] = bb.x; XmT[c4 + 1][row] = bb.y;
        XmT[c4 + 2][row] = bb.z; XmT[c4 + 3][row] = bb.w;
    }
    __syncthreads();
    const int tr = (t >> 4) << 2;     // n rows   0..60
    const int tc = (t & 15) << 2;     // m cols   0..60
    float acc[4][4] = {};
    #pragma unroll
    for (int k = 0; k < 64; ++k) {
        float a[4], c[4];
        *(float4*)a = *(const float4*)&XnT[k][tr];
        *(float4*)c = *(const float4*)&XmT[k][tc];
        #pragma unroll
        for (int r = 0; r < 4; ++r)
            #pragma unroll
            for (int j = 0; j < 4; ++j)
                acc[r][j] += a[r] * c[j];
    }
    const float sc = scale[b];
    const float* sqb = sq + b * NN;
    float sm[4];
    #pragma unroll
    for (int j = 0; j < 4; ++j) sm[j] = sqb[mt * 64 + tc + j];
    #pragma unroll
    for (int r = 0; r < 4; ++r) {
        const int gn = nt * 64 + tr + r;
        const float sn = sqb[gn];
        float4 o;
        o.x = __expf(sc * (sn + sm[0] - 2.0f * acc[r][0]));
        o.y = __expf(sc * (sn + sm[1] - 2.0f * acc[r][1]));
        o.z = __expf(sc * (sn + sm[2] - 2.0f * acc[r][2]));
        o.w = __expf(sc * (sn + sm[3] - 2.0f * acc[r][3]));
        *(float4*)(K + ((size_t)b * NN + gn) * NN + mt * 64 + tc) = o;
    }
}

// ---------------------------------------------------------------- sink_pass
// MODE 0: u[n] = (w[n]+1e-16) / sum_m K[n,m] * v[m]   (vin = v, out = u)
// MODE 1: v[m] = (1/N)        / sum_n K[m,n] * u[n]   (vin = u, out = v)
// (K symmetric -> both are row traversals.)  One wave per row.
template <int MODE>
__global__ __launch_bounds__(256) void sink_pass(const float* __restrict__ K,
                                                 const float* __restrict__ vin,
                                                 const float* __restrict__ wts,
                                                 float* __restrict__ out) {
    const int row  = blockIdx.x * 4 + (threadIdx.x >> 6);
    const int lane = threadIdx.x & 63;
    const float* Kr = K + (size_t)row * NN;
    const float* vb = vin + (size_t)(row >> 11) * NN;
    float acc = 0.f;
    #pragma unroll
    for (int it = 0; it < NN / 256; ++it) {
        const int m = (lane << 2) + (it << 8);
        float4 k4 = *(const float4*)(Kr + m);
        float4 v4 = *(const float4*)(vb + m);
        acc += k4.x * v4.x + k4.y * v4.y + k4.z * v4.z + k4.w * v4.w;
    }
    #pragma unroll
    for (int off = 32; off > 0; off >>= 1) acc += __shfl_down(acc, off);
    if (lane == 0) {
        const float num = (MODE == 0) ? (wts[row] + 1e-16f) : (1.0f / (float)NN);
        out[row] = num / acc;
    }
}

// ---------------------------------------------------------------- out_gemm
// new_particles[b,m,d] = N * v[m] * sum_n u[n]*K[m,n]*x[n,d]
// 64(m) x 64(d) tile per block, loop over n tiles of 64.
__global__ __launch_bounds__(256) void out_gemm(const float* __restrict__ K,
                                                const float* __restrict__ X,
                                                const float* __restrict__ u,
                                                const float* __restrict__ v,
                                                float* __restrict__ outP) {
    __shared__ float Ps[64][68];    // [m-row][n-col]  (u folded in)
    __shared__ float Xs[64][68];    // [n-row][d]
    const int b = blockIdx.y, mt = blockIdx.x;
    const int t = threadIdx.x;
    const int tr = (t >> 4) << 2;   // m rows 0..60
    const int tc = (t & 15) << 2;   // d cols 0..60
    const float* ub = u + (size_t)b * NN;
    const float* Xb = X + (size_t)b * NN * DD;
    const float* Kb = K + ((size_t)b * NN + mt * 64) * NN;
    float acc[4][4] = {};
    for (int ntile = 0; ntile < NN / 64; ++ntile) {
        __syncthreads();
        #pragma unroll
        for (int i = 0; i < 4; ++i) {
            int f   = t + i * 256;
            int row = f >> 4;
            int c4  = (f & 15) << 2;
            float4 k4 = *(const float4*)(Kb + (size_t)row * NN + ntile * 64 + c4);
            float4 u4 = *(const float4*)(ub + ntile * 64 + c4);
            *(float4*)&Ps[row][c4] =
                make_float4(k4.x * u4.x, k4.y * u4.y, k4.z * u4.z, k4.w * u4.w);
            *(float4*)&Xs[row][c4] =
                *(const float4*)(Xb + (size_t)(ntile * 64 + row) * DD + c4);
        }
        __syncthreads();
        #pragma unroll
        for (int c = 0; c < 64; c += 4) {
            float a[4][4], x[4][4];
            #pragma unroll
            for (int r = 0; r < 4; ++r)
                *(float4*)a[r] = *(const float4*)&Ps[tr + r][c];
            #pragma unroll
            for (int cc = 0; cc < 4; ++cc)
                *(float4*)x[cc] = *(const float4*)&Xs[c + cc][tc];
            #pragma unroll
            for (int r = 0; r < 4; ++r)
                #pragma unroll
                for (int cc = 0; cc < 4; ++cc)
                    #pragma unroll
                    for (int j = 0; j < 4; ++j)
                        acc[r][j] += a[r][cc] * x[cc][j];
        }
    }
    #pragma unroll
    for (int r = 0; r < 4; ++r) {
        const int gm = mt * 64 + tr + r;
        const float vr = (float)NN * v[(size_t)b * NN + gm];
        float4 o = make_float4(vr * acc[r][0], vr * acc[r][1],
                               vr * acc[r][2], vr * acc[r][3]);
        *(float4*)(outP + ((size_t)b * NN + gm) * DD + tc) = o;
    }
}

// ---------------------------------------------------------------- launch
extern "C" void kernel_launch(void* const* d_in, const int* in_sizes, int n_in,
                              void* d_out, int out_size, void* d_ws, size_t ws_size,
                              hipStream_t stream) {
    const float* X = (const float*)d_in[0];   // particles [B,N,D]
    const float* W = (const float*)d_in[1];   // weights   [B,N]
    float* outP = (float*)d_out;                       // [B,N,D]
    float* outW = outP + (size_t)BB * NN * DD;         // [B,N]

    float* ws = (float*)d_ws;
    const size_t need = ((size_t)BB * NN * NN + BB * NN + 16 + 2 * BB * NN)
                        * sizeof(float);
    if (ws_size < need) return;   // workspace too small -> fail loudly

    float* K     = ws;
    float* sq    = K + (size_t)BB * NN * NN;
    float* scale = sq + BB * NN;
    float* u     = scale + 16;
    float* v     = u + BB * NN;

    row_sq<<<dim3(BB * NN / 4), 256, 0, stream>>>(X, sq);
    batch_stats<<<dim3(BB), 256, 0, stream>>>(X, sq, scale);
    init_vw<<<dim3(BB * NN / 256), 256, 0, stream>>>(v, outW);
    build_K<<<dim3(NN / 64, NN / 64, BB), 256, 0, stream>>>(X, sq, scale, K);
    for (int i = 0; i < ITERS; ++i) {
        sink_pass<0><<<dim3(BB * NN / 4), 256, 0, stream>>>(K, v, W, u);
        sink_pass<1><<<dim3(BB * NN / 4), 256, 0, stream>>>(K, u, W, v);
    }
    out_gemm<<<dim3(NN / 64, BB), 256, 0, stream>>>(K, X, u, v, outP);
}

// Round 2
// 568.807 us; speedup vs baseline: 1.1624x; 1.1624x over previous
//
#include <hip/hip_runtime.h>

#define BB 8
#define NN 2048
#define DD 64
constexpr float EPS = 0.1f;
constexpr int ITERS = 10;

// ---------------------------------------------------------------- stats1
// Per 64-row chunk: sq[row] (= sum_d x^2), partial column-sum (per d),
// partial total-sq. Grid = BB*32 blocks of 256.
__global__ __launch_bounds__(256) void stats1(const float* __restrict__ X,
                                              float* __restrict__ sq,
                                              float* __restrict__ pcol,
                                              float* __restrict__ ptot) {
    const int blk = blockIdx.x;          // 0 .. BB*32-1
    const int b   = blk >> 5;
    const int r0  = (blk & 31) * 64;
    const int t = threadIdx.x, w = t >> 6, lane = t & 63;
    const float* Xb = X + (size_t)b * NN * DD;
    float cs = 0.f, sqtot = 0.f;
    #pragma unroll
    for (int i = w; i < 64; i += 4) {
        const int row = r0 + i;
        float x = Xb[(size_t)row * DD + lane];
        cs += x;
        float s = x * x;
        #pragma unroll
        for (int off = 32; off > 0; off >>= 1) s += __shfl_down(s, off);
        if (lane == 0) { sq[b * NN + row] = s; sqtot += s; }
    }
    __shared__ float colS[4][64];
    __shared__ float totS[4];
    colS[w][lane] = cs;
    if (lane == 0) totS[w] = sqtot;
    __syncthreads();
    if (t < 64)
        pcol[blk * 64 + t] = colS[0][t] + colS[1][t] + colS[2][t] + colS[3][t];
    if (t == 0)
        ptot[blk] = totS[0] + totS[1] + totS[2] + totS[3];
}

// ---------------------------------------------------------------- stats2
// Combine 32 partials per batch -> scale[b] = -1/(C_mean*eps)
// C_mean = 2*T/N - 2*|colsum|^2/N^2 + 1e-8
__global__ void stats2(const float* __restrict__ pcol,
                       const float* __restrict__ ptot,
                       float* __restrict__ scale) {
    const int b = blockIdx.x, t = threadIdx.x;   // 64 threads
    float c = 0.f;
    #pragma unroll
    for (int p = 0; p < 32; ++p) c += pcol[(b * 32 + p) * 64 + t];
    float s2 = c * c;
    #pragma unroll
    for (int off = 32; off > 0; off >>= 1) s2 += __shfl_down(s2, off);
    if (t == 0) {
        float T = 0.f;
        #pragma unroll
        for (int p = 0; p < 32; ++p) T += ptot[b * 32 + p];
        float cmean = 2.0f * T / (float)NN
                    - 2.0f * s2 / ((float)NN * (float)NN) + 1e-8f;
        scale[b] = -1.0f / (cmean * EPS);
    }
}

// ---------------------------------------------------------------- init
__global__ void init_vw(float* __restrict__ v, float* __restrict__ outW) {
    const int i = blockIdx.x * 256 + threadIdx.x;
    v[i]    = 1.0f;
    outW[i] = 1.0f / (float)NN;
}

// ---------------------------------------------------------------- build_K
// K[b,n,m] = exp(scale[b] * (sq[n] + sq[m] - 2 * x_n . x_m))
__global__ __launch_bounds__(256) void build_K(const float* __restrict__ X,
                                               const float* __restrict__ sq,
                                               const float* __restrict__ scale,
                                               float* __restrict__ K) {
    __shared__ float XnT[64][68];   // [k][n-row]
    __shared__ float XmT[64][68];   // [k][m-row]
    const int b = blockIdx.z, nt = blockIdx.y, mt = blockIdx.x;
    const int t = threadIdx.x;
    const float* Xb = X + (size_t)b * NN * DD;
    #pragma unroll
    for (int i = 0; i < 4; ++i) {
        int f   = t + i * 256;
        int row = f >> 4;
        int c4  = (f & 15) << 2;
        float4 a = *(const float4*)(Xb + (size_t)(nt * 64 + row) * DD + c4);
        XnT[c4 + 0][row] = a.x; XnT[c4 + 1][row] = a.y;
        XnT[c4 + 2][row] = a.z; XnT[c4 + 3][row] = a.w;
        float4 bb = *(const float4*)(Xb + (size_t)(mt * 64 + row) * DD + c4);
        XmT[c4 + 0][row] = bb.x; XmT[c4 + 1][row] = bb.y;
        XmT[c4 + 2][row] = bb.z; XmT[c4 + 3][row] = bb.w;
    }
    __syncthreads();
    const int tr = (t >> 4) << 2;
    const int tc = (t & 15) << 2;
    float acc[4][4] = {};
    #pragma unroll
    for (int k = 0; k < 64; ++k) {
        float a[4], c[4];
        *(float4*)a = *(const float4*)&XnT[k][tr];
        *(float4*)c = *(const float4*)&XmT[k][tc];
        #pragma unroll
        for (int r = 0; r < 4; ++r)
            #pragma unroll
            for (int j = 0; j < 4; ++j)
                acc[r][j] += a[r] * c[j];
    }
    const float sc = scale[b];
    const float* sqb = sq + b * NN;
    float sm[4];
    #pragma unroll
    for (int j = 0; j < 4; ++j) sm[j] = sqb[mt * 64 + tc + j];
    #pragma unroll
    for (int r = 0; r < 4; ++r) {
        const int gn = nt * 64 + tr + r;
        const float sn = sqb[gn];
        float4 o;
        o.x = __expf(sc * (sn + sm[0] - 2.0f * acc[r][0]));
        o.y = __expf(sc * (sn + sm[1] - 2.0f * acc[r][1]));
        o.z = __expf(sc * (sn + sm[2] - 2.0f * acc[r][2]));
        o.w = __expf(sc * (sn + sm[3] - 2.0f * acc[r][3]));
        *(float4*)(K + ((size_t)b * NN + gn) * NN + mt * 64 + tc) = o;
    }
}

// ---------------------------------------------------------------- sink_pass
// MODE 0: u[n] = (w[n]+1e-16) / sum_m K[n,m]*v[m]
// MODE 1: v[m] = (1/N)        / sum_n K[m,n]*u[n]   (K symmetric -> row scan)
template <int MODE>
__global__ __launch_bounds__(256) void sink_pass(const float* __restrict__ K,
                                                 const float* __restrict__ vin,
                                                 const float* __restrict__ wts,
                                                 float* __restrict__ out) {
    const int row  = blockIdx.x * 4 + (threadIdx.x >> 6);
    const int lane = threadIdx.x & 63;
    const float* Kr = K + (size_t)row * NN;
    const float* vb = vin + (size_t)(row >> 11) * NN;
    float acc = 0.f;
    #pragma unroll
    for (int it = 0; it < NN / 256; ++it) {
        const int m = (lane << 2) + (it << 8);
        float4 k4 = *(const float4*)(Kr + m);
        float4 v4 = *(const float4*)(vb + m);
        acc += k4.x * v4.x + k4.y * v4.y + k4.z * v4.z + k4.w * v4.w;
    }
    #pragma unroll
    for (int off = 32; off > 0; off >>= 1) acc += __shfl_down(acc, off);
    if (lane == 0) {
        const float num = (MODE == 0) ? (wts[row] + 1e-16f) : (1.0f / (float)NN);
        out[row] = num / acc;
    }
}

// ---------------------------------------------------------------- out_gemm
// new_particles[b,m,d] = N * v[m] * sum_n u[n]*K[m,n]*x[n,d]
__global__ __launch_bounds__(256) void out_gemm(const float* __restrict__ K,
                                                const float* __restrict__ X,
                                                const float* __restrict__ u,
                                                const float* __restrict__ v,
                                                float* __restrict__ outP) {
    __shared__ float Ps[64][68];
    __shared__ float Xs[64][68];
    const int b = blockIdx.y, mt = blockIdx.x;
    const int t = threadIdx.x;
    const int tr = (t >> 4) << 2;
    const int tc = (t & 15) << 2;
    const float* ub = u + (size_t)b * NN;
    const float* Xb = X + (size_t)b * NN * DD;
    const float* Kb = K + ((size_t)b * NN + mt * 64) * NN;
    float acc[4][4] = {};
    for (int ntile = 0; ntile < NN / 64; ++ntile) {
        __syncthreads();
        #pragma unroll
        for (int i = 0; i < 4; ++i) {
            int f   = t + i * 256;
            int row = f >> 4;
            int c4  = (f & 15) << 2;
            float4 k4 = *(const float4*)(Kb + (size_t)row * NN + ntile * 64 + c4);
            float4 u4 = *(const float4*)(ub + ntile * 64 + c4);
            *(float4*)&Ps[row][c4] =
                make_float4(k4.x * u4.x, k4.y * u4.y, k4.z * u4.z, k4.w * u4.w);
            *(float4*)&Xs[row][c4] =
                *(const float4*)(Xb + (size_t)(ntile * 64 + row) * DD + c4);
        }
        __syncthreads();
        #pragma unroll
        for (int c = 0; c < 64; c += 4) {
            float a[4][4], x[4][4];
            #pragma unroll
            for (int r = 0; r < 4; ++r)
                *(float4*)a[r] = *(const float4*)&Ps[tr + r][c];
            #pragma unroll
            for (int cc = 0; cc < 4; ++cc)
                *(float4*)x[cc] = *(const float4*)&Xs[c + cc][tc];
            #pragma unroll
            for (int r = 0; r < 4; ++r)
                #pragma unroll
                for (int cc = 0; cc < 4; ++cc)
                    #pragma unroll
                    for (int j = 0; j < 4; ++j)
                        acc[r][j] += a[r][cc] * x[cc][j];
        }
    }
    #pragma unroll
    for (int r = 0; r < 4; ++r) {
        const int gm = mt * 64 + tr + r;
        const float vr = (float)NN * v[(size_t)b * NN + gm];
        float4 o = make_float4(vr * acc[r][0], vr * acc[r][1],
                               vr * acc[r][2], vr * acc[r][3]);
        *(float4*)(outP + ((size_t)b * NN + gm) * DD + tc) = o;
    }
}

// ---------------------------------------------------------------- launch
extern "C" void kernel_launch(void* const* d_in, const int* in_sizes, int n_in,
                              void* d_out, int out_size, void* d_ws, size_t ws_size,
                              hipStream_t stream) {
    const float* X = (const float*)d_in[0];   // particles [B,N,D]
    const float* W = (const float*)d_in[1];   // weights   [B,N]
    float* outP = (float*)d_out;                       // [B,N,D]
    float* outW = outP + (size_t)BB * NN * DD;         // [B,N]

    float* ws = (float*)d_ws;
    const size_t need = ((size_t)BB * NN * NN + BB * NN + 16 + 2 * BB * NN
                         + BB * 32 * 64 + BB * 32) * sizeof(float);
    if (ws_size < need) return;

    float* K     = ws;
    float* sq    = K + (size_t)BB * NN * NN;
    float* scale = sq + BB * NN;
    float* u     = scale + 16;
    float* v     = u + BB * NN;
    float* pcol  = v + BB * NN;
    float* ptot  = pcol + BB * 32 * 64;

    stats1<<<dim3(BB * 32), 256, 0, stream>>>(X, sq, pcol, ptot);
    stats2<<<dim3(BB), 64, 0, stream>>>(pcol, ptot, scale);
    init_vw<<<dim3(BB * NN / 256), 256, 0, stream>>>(v, outW);
    build_K<<<dim3(NN / 64, NN / 64, BB), 256, 0, stream>>>(X, sq, scale, K);
    for (int i = 0; i < ITERS; ++i) {
        sink_pass<0><<<dim3(BB * NN / 4), 256, 0, stream>>>(K, v, W, u);
        sink_pass<1><<<dim3(BB * NN / 4), 256, 0, stream>>>(K, u, W, v);
    }
    out_gemm<<<dim3(NN / 64, BB), 256, 0, stream>>>(K, X, u, v, outP);
}

// Round 3
// 390.531 us; speedup vs baseline: 1.6931x; 1.4565x over previous
//
#include <hip/hip_runtime.h>

#define BB 8
#define NN 2048
#define DD 64
#define NC 8            // split-K chunks for out_gemm
constexpr float EPS = 0.1f;
constexpr int ITERS = 10;

typedef _Float16 h4 __attribute__((ext_vector_type(4)));
typedef _Float16 h8 __attribute__((ext_vector_type(8)));

// ---------------------------------------------------------------- stats1
__global__ __launch_bounds__(256) void stats1(const float* __restrict__ X,
                                              float* __restrict__ sq,
                                              float* __restrict__ pcol,
                                              float* __restrict__ ptot) {
    const int blk = blockIdx.x;          // 0 .. BB*32-1
    const int b   = blk >> 5;
    const int r0  = (blk & 31) * 64;
    const int t = threadIdx.x, w = t >> 6, lane = t & 63;
    const float* Xb = X + (size_t)b * NN * DD;
    float cs = 0.f, sqtot = 0.f;
    #pragma unroll
    for (int i = w; i < 64; i += 4) {
        const int row = r0 + i;
        float x = Xb[(size_t)row * DD + lane];
        cs += x;
        float s = x * x;
        #pragma unroll
        for (int off = 32; off > 0; off >>= 1) s += __shfl_down(s, off);
        if (lane == 0) { sq[b * NN + row] = s; sqtot += s; }
    }
    __shared__ float colS[4][64];
    __shared__ float totS[4];
    colS[w][lane] = cs;
    if (lane == 0) totS[w] = sqtot;
    __syncthreads();
    if (t < 64)
        pcol[blk * 64 + t] = colS[0][t] + colS[1][t] + colS[2][t] + colS[3][t];
    if (t == 0)
        ptot[blk] = totS[0] + totS[1] + totS[2] + totS[3];
}

// ---------------------------------------------------------------- stats2
__global__ void stats2(const float* __restrict__ pcol,
                       const float* __restrict__ ptot,
                       float* __restrict__ scale) {
    const int b = blockIdx.x, t = threadIdx.x;   // 64 threads
    float c = 0.f;
    #pragma unroll
    for (int p = 0; p < 32; ++p) c += pcol[(b * 32 + p) * 64 + t];
    float s2 = c * c;
    #pragma unroll
    for (int off = 32; off > 0; off >>= 1) s2 += __shfl_down(s2, off);
    if (t == 0) {
        float T = 0.f;
        #pragma unroll
        for (int p = 0; p < 32; ++p) T += ptot[b * 32 + p];
        float cmean = 2.0f * T / (float)NN
                    - 2.0f * s2 / ((float)NN * (float)NN) + 1e-8f;
        scale[b] = -1.0f / (cmean * EPS);
    }
}

// ---------------------------------------------------------------- init
__global__ void init_vw(float* __restrict__ v, float* __restrict__ outW) {
    const int i = blockIdx.x * 256 + threadIdx.x;
    v[i]    = 1.0f;
    outW[i] = 1.0f / (float)NN;
}

// ---------------------------------------------------------------- build_K
// K[b,n,m] = exp(scale[b]*(sq[n]+sq[m]-2*x_n.x_m)) stored fp16
__global__ __launch_bounds__(256) void build_K(const float* __restrict__ X,
                                               const float* __restrict__ sq,
                                               const float* __restrict__ scale,
                                               _Float16* __restrict__ K) {
    __shared__ float XnT[64][68];
    __shared__ float XmT[64][68];
    const int b = blockIdx.z, nt = blockIdx.y, mt = blockIdx.x;
    const int t = threadIdx.x;
    const float* Xb = X + (size_t)b * NN * DD;
    #pragma unroll
    for (int i = 0; i < 4; ++i) {
        int f   = t + i * 256;
        int row = f >> 4;
        int c4  = (f & 15) << 2;
        float4 a = *(const float4*)(Xb + (size_t)(nt * 64 + row) * DD + c4);
        XnT[c4 + 0][row] = a.x; XnT[c4 + 1][row] = a.y;
        XnT[c4 + 2][row] = a.z; XnT[c4 + 3][row] = a.w;
        float4 bb = *(const float4*)(Xb + (size_t)(mt * 64 + row) * DD + c4);
        XmT[c4 + 0][row] = bb.x; XmT[c4 + 1][row] = bb.y;
        XmT[c4 + 2][row] = bb.z; XmT[c4 + 3][row] = bb.w;
    }
    __syncthreads();
    const int tr = (t >> 4) << 2;
    const int tc = (t & 15) << 2;
    float acc[4][4] = {};
    #pragma unroll
    for (int k = 0; k < 64; ++k) {
        float a[4], c[4];
        *(float4*)a = *(const float4*)&XnT[k][tr];
        *(float4*)c = *(const float4*)&XmT[k][tc];
        #pragma unroll
        for (int r = 0; r < 4; ++r)
            #pragma unroll
            for (int j = 0; j < 4; ++j)
                acc[r][j] += a[r] * c[j];
    }
    const float sc = scale[b];
    const float* sqb = sq + b * NN;
    float sm[4];
    #pragma unroll
    for (int j = 0; j < 4; ++j) sm[j] = sqb[mt * 64 + tc + j];
    #pragma unroll
    for (int r = 0; r < 4; ++r) {
        const int gn = nt * 64 + tr + r;
        const float sn = sqb[gn];
        h4 o;
        o[0] = (_Float16)__expf(sc * (sn + sm[0] - 2.0f * acc[r][0]));
        o[1] = (_Float16)__expf(sc * (sn + sm[1] - 2.0f * acc[r][1]));
        o[2] = (_Float16)__expf(sc * (sn + sm[2] - 2.0f * acc[r][2]));
        o[3] = (_Float16)__expf(sc * (sn + sm[3] - 2.0f * acc[r][3]));
        *(h4*)(K + ((size_t)b * NN + gn) * NN + mt * 64 + tc) = o;
    }
}

// ---------------------------------------------------------------- sink_pass
// MODE 0: u[n] = (w[n]+1e-16) / sum_m K[n,m]*v[m]
// MODE 1: v[m] = (1/N)        / sum_n K[m,n]*u[n]   (K symmetric)
template <int MODE>
__global__ __launch_bounds__(256) void sink_pass(const _Float16* __restrict__ K,
                                                 const float* __restrict__ vin,
                                                 const float* __restrict__ wts,
                                                 float* __restrict__ out) {
    const int row  = blockIdx.x * 4 + (threadIdx.x >> 6);
    const int lane = threadIdx.x & 63;
    const _Float16* Kr = K + (size_t)row * NN;
    const float* vb = vin + (size_t)(row >> 11) * NN;
    float acc = 0.f;
    #pragma unroll
    for (int it = 0; it < NN / 512; ++it) {
        const int m = (lane << 3) + (it << 9);
        h8 k8 = *(const h8*)(Kr + m);
        float4 va = *(const float4*)(vb + m);
        float4 vc = *(const float4*)(vb + m + 4);
        acc += (float)k8[0] * va.x + (float)k8[1] * va.y
             + (float)k8[2] * va.z + (float)k8[3] * va.w
             + (float)k8[4] * vc.x + (float)k8[5] * vc.y
             + (float)k8[6] * vc.z + (float)k8[7] * vc.w;
    }
    #pragma unroll
    for (int off = 32; off > 0; off >>= 1) acc += __shfl_down(acc, off);
    if (lane == 0) {
        const float num = (MODE == 0) ? (wts[row] + 1e-16f) : (1.0f / (float)NN);
        out[row] = num / acc;
    }
}

// ---------------------------------------------------------------- out_gemm
// Partial: pbuf[nc,b,m,d] = sum_{n in chunk nc} u[n]*K[m,n]*x[n,d]
__global__ __launch_bounds__(256) void out_gemm(const _Float16* __restrict__ K,
                                                const float* __restrict__ X,
                                                const float* __restrict__ u,
                                                float* __restrict__ pbuf) {
    __shared__ float Ps[64][68];
    __shared__ float Xs[64][68];
    const int b = blockIdx.z, nc = blockIdx.y, mt = blockIdx.x;
    const int t = threadIdx.x;
    const int tr = (t >> 4) << 2;
    const int tc = (t & 15) << 2;
    const float* ub = u + (size_t)b * NN;
    const float* Xb = X + (size_t)b * NN * DD;
    const _Float16* Kb = K + ((size_t)b * NN + mt * 64) * NN;
    float acc[4][4] = {};
    for (int st = 0; st < (NN / NC) / 64; ++st) {
        const int n0 = nc * (NN / NC) + st * 64;
        __syncthreads();
        #pragma unroll
        for (int i = 0; i < 2; ++i) {           // K tile 64x64 fp16
            int f   = t + i * 256;
            int row = f >> 3;
            int c8  = (f & 7) << 3;
            h8 k8 = *(const h8*)(Kb + (size_t)row * NN + n0 + c8);
            float4 ua = *(const float4*)(ub + n0 + c8);
            float4 uc = *(const float4*)(ub + n0 + c8 + 4);
            Ps[row][c8 + 0] = (float)k8[0] * ua.x;
            Ps[row][c8 + 1] = (float)k8[1] * ua.y;
            Ps[row][c8 + 2] = (float)k8[2] * ua.z;
            Ps[row][c8 + 3] = (float)k8[3] * ua.w;
            Ps[row][c8 + 4] = (float)k8[4] * uc.x;
            Ps[row][c8 + 5] = (float)k8[5] * uc.y;
            Ps[row][c8 + 6] = (float)k8[6] * uc.z;
            Ps[row][c8 + 7] = (float)k8[7] * uc.w;
        }
        #pragma unroll
        for (int i = 0; i < 4; ++i) {           // X tile 64x64 fp32
            int f   = t + i * 256;
            int row = f >> 4;
            int c4  = (f & 15) << 2;
            *(float4*)&Xs[row][c4] =
                *(const float4*)(Xb + (size_t)(n0 + row) * DD + c4);
        }
        __syncthreads();
        #pragma unroll
        for (int c = 0; c < 64; c += 4) {
            float a[4][4], x[4][4];
            #pragma unroll
            for (int r = 0; r < 4; ++r)
                *(float4*)a[r] = *(const float4*)&Ps[tr + r][c];
            #pragma unroll
            for (int cc = 0; cc < 4; ++cc)
                *(float4*)x[cc] = *(const float4*)&Xs[c + cc][tc];
            #pragma unroll
            for (int r = 0; r < 4; ++r)
                #pragma unroll
                for (int cc = 0; cc < 4; ++cc)
                    #pragma unroll
                    for (int j = 0; j < 4; ++j)
                        acc[r][j] += a[r][cc] * x[cc][j];
        }
    }
    float* pb = pbuf + (size_t)nc * BB * NN * DD;
    #pragma unroll
    for (int r = 0; r < 4; ++r) {
        const int gm = mt * 64 + tr + r;
        *(float4*)(pb + ((size_t)b * NN + gm) * DD + tc) = *(float4*)acc[r];
    }
}

// ---------------------------------------------------------------- out_reduce
// out[b,m,d] = N * v[b,m] * sum_nc pbuf[nc,b,m,d]
__global__ __launch_bounds__(256) void out_reduce(const float* __restrict__ pbuf,
                                                  const float* __restrict__ v,
                                                  float* __restrict__ outP) {
    const int idx = blockIdx.x * 256 + threadIdx.x;   // per float4
    const int d4 = idx & (DD / 4 - 1);
    const int bm = idx >> 4;                           // b*NN + m
    const float vr = (float)NN * v[bm];
    float4 s = make_float4(0.f, 0.f, 0.f, 0.f);
    #pragma unroll
    for (int nc = 0; nc < NC; ++nc) {
        float4 p = *(const float4*)(pbuf + (size_t)nc * BB * NN * DD
                                    + (size_t)bm * DD + d4 * 4);
        s.x += p.x; s.y += p.y; s.z += p.z; s.w += p.w;
    }
    *(float4*)(outP + (size_t)bm * DD + d4 * 4) =
        make_float4(vr * s.x, vr * s.y, vr * s.z, vr * s.w);
}

// ---------------------------------------------------------------- launch
extern "C" void kernel_launch(void* const* d_in, const int* in_sizes, int n_in,
                              void* d_out, int out_size, void* d_ws, size_t ws_size,
                              hipStream_t stream) {
    const float* X = (const float*)d_in[0];   // particles [B,N,D]
    const float* W = (const float*)d_in[1];   // weights   [B,N]
    float* outP = (float*)d_out;                       // [B,N,D]
    float* outW = outP + (size_t)BB * NN * DD;         // [B,N]

    float* ws = (float*)d_ws;
    const size_t nfloats = (size_t)BB * NN          // sq
                         + 16                       // scale
                         + 2 * (size_t)BB * NN      // u, v
                         + (size_t)BB * 32 * 64 + BB * 32   // pcol, ptot
                         + (size_t)NC * BB * NN * DD;       // pbuf
    const size_t need = nfloats * 4 + (size_t)BB * NN * NN * 2;
    if (ws_size < need) return;

    float* sq    = ws;
    float* scale = sq + (size_t)BB * NN;
    float* u     = scale + 16;
    float* v     = u + (size_t)BB * NN;
    float* pcol  = v + (size_t)BB * NN;
    float* ptot  = pcol + (size_t)BB * 32 * 64;
    float* pbuf  = ptot + BB * 32;
    _Float16* K  = (_Float16*)(pbuf + (size_t)NC * BB * NN * DD);

    stats1<<<dim3(BB * 32), 256, 0, stream>>>(X, sq, pcol, ptot);
    stats2<<<dim3(BB), 64, 0, stream>>>(pcol, ptot, scale);
    init_vw<<<dim3(BB * NN / 256), 256, 0, stream>>>(v, outW);
    build_K<<<dim3(NN / 64, NN / 64, BB), 256, 0, stream>>>(X, sq, scale, K);
    for (int i = 0; i < ITERS; ++i) {
        sink_pass<0><<<dim3(BB * NN / 4), 256, 0, stream>>>(K, v, W, u);
        sink_pass<1><<<dim3(BB * NN / 4), 256, 0, stream>>>(K, u, W, v);
    }
    out_gemm<<<dim3(NN / 64, NC, BB), 256, 0, stream>>>(K, X, u, pbuf);
    out_reduce<<<dim3(BB * NN * DD / 4 / 256), 256, 0, stream>>>(pbuf, v, outP);
}

// Round 4
// 288.820 us; speedup vs baseline: 2.2893x; 1.3522x over previous
//
#include <hip/hip_runtime.h>

#define BB 8
#define NN 2048
#define DD 64
#define NC 8            // split-K chunks for out_gemm
constexpr float EPS = 0.1f;
constexpr int ITERS = 10;
constexpr float KSCALE = 4096.0f;   // off-diag fp8 scale; diag handled analytically

typedef short bf16x8 __attribute__((ext_vector_type(8)));
typedef float f32x16 __attribute__((ext_vector_type(16)));
typedef float f32x2  __attribute__((ext_vector_type(2)));

// ---------------------------------------------------------------- fp8 helpers
__device__ inline float e4m3_to_f32_manual(unsigned int b) {
    unsigned int e = (b >> 3) & 15u, m = b & 7u;
    float v;
    if (e == 0) v = (float)m * 0.001953125f;              // m * 2^-9
    else        v = __uint_as_float(((e + 120u) << 23) | (m << 20));
    return (b & 0x80u) ? -v : v;
}

__device__ inline void fp8x8_to_f32(unsigned int lo, unsigned int hi, float* o) {
#if __has_builtin(__builtin_amdgcn_cvt_pk_f32_fp8)
    f32x2 p;
    p = __builtin_amdgcn_cvt_pk_f32_fp8(lo, false); o[0] = p[0]; o[1] = p[1];
    p = __builtin_amdgcn_cvt_pk_f32_fp8(lo, true);  o[2] = p[0]; o[3] = p[1];
    p = __builtin_amdgcn_cvt_pk_f32_fp8(hi, false); o[4] = p[0]; o[5] = p[1];
    p = __builtin_amdgcn_cvt_pk_f32_fp8(hi, true);  o[6] = p[0]; o[7] = p[1];
#else
    o[0] = e4m3_to_f32_manual(lo & 255u);  o[1] = e4m3_to_f32_manual((lo >> 8) & 255u);
    o[2] = e4m3_to_f32_manual((lo >> 16) & 255u); o[3] = e4m3_to_f32_manual(lo >> 24);
    o[4] = e4m3_to_f32_manual(hi & 255u);  o[5] = e4m3_to_f32_manual((hi >> 8) & 255u);
    o[6] = e4m3_to_f32_manual((hi >> 16) & 255u); o[7] = e4m3_to_f32_manual(hi >> 24);
#endif
}

__device__ inline unsigned char f32_to_e4m3(float f) {   // f in [0, 448]
#if __has_builtin(__builtin_amdgcn_cvt_pk_fp8_f32)
    return (unsigned char)(__builtin_amdgcn_cvt_pk_fp8_f32(f, f, 0, false) & 0xFF);
#else
    if (!(f > 0.f)) return 0;
    if (f >= 448.f) return 0x7E;
    int e; float m = frexpf(f, &e);            // f = m*2^e, m in [0.5,1)
    if (e >= -5) {                              // normal: f >= 2^-6
        int mant = (int)roundf(m * 16.f) - 8;   // 0..8
        int ef = e + 6;
        if (mant == 8) { mant = 0; ef += 1; }
        if (ef >= 16) return 0x7E;
        return (unsigned char)((ef << 3) | mant);
    }
    int mant = (int)roundf(f * 512.f);          // subnormal
    if (mant >= 8) return 0x08;
    return (unsigned char)mant;
#endif
}

// ---------------------------------------------------------------- stats1
// Rounds X to bf16 (RNE), writes Xbf; sq/colsums computed from ROUNDED values
// so that the MFMA gram diagonal satisfies C_nn ~= 0 exactly.
__global__ __launch_bounds__(256) void stats1(const float* __restrict__ X,
                                              unsigned short* __restrict__ Xbf,
                                              float* __restrict__ sq,
                                              float* __restrict__ pcol,
                                              float* __restrict__ ptot) {
    const int blk = blockIdx.x;          // 0 .. BB*32-1
    const int b   = blk >> 5;
    const int r0  = (blk & 31) * 64;
    const int t = threadIdx.x, w = t >> 6, lane = t & 63;
    const float* Xb = X + (size_t)b * NN * DD;
    unsigned short* Xbfb = Xbf + (size_t)b * NN * DD;
    float cs = 0.f, sqtot = 0.f;
    #pragma unroll
    for (int i = w; i < 64; i += 4) {
        const int row = r0 + i;
        float x = Xb[(size_t)row * DD + lane];
        unsigned int ub = __float_as_uint(x);
        ub += 0x7FFFu + ((ub >> 16) & 1u);          // RNE to bf16
        unsigned short hb = (unsigned short)(ub >> 16);
        Xbfb[(size_t)row * DD + lane] = hb;
        float xr = __uint_as_float((unsigned int)hb << 16);
        cs += xr;
        float s = xr * xr;
        #pragma unroll
        for (int off = 32; off > 0; off >>= 1) s += __shfl_down(s, off);
        if (lane == 0) { sq[b * NN + row] = s; sqtot += s; }
    }
    __shared__ float colS[4][64];
    __shared__ float totS[4];
    colS[w][lane] = cs;
    if (lane == 0) totS[w] = sqtot;
    __syncthreads();
    if (t < 64)
        pcol[blk * 64 + t] = colS[0][t] + colS[1][t] + colS[2][t] + colS[3][t];
    if (t == 0)
        ptot[blk] = totS[0] + totS[1] + totS[2] + totS[3];
}

// ---------------------------------------------------------------- stats2
__global__ void stats2(const float* __restrict__ pcol,
                       const float* __restrict__ ptot,
                       float* __restrict__ scale) {
    const int b = blockIdx.x, t = threadIdx.x;   // 64 threads
    float c = 0.f;
    #pragma unroll
    for (int p = 0; p < 32; ++p) c += pcol[(b * 32 + p) * 64 + t];
    float s2 = c * c;
    #pragma unroll
    for (int off = 32; off > 0; off >>= 1) s2 += __shfl_down(s2, off);
    if (t == 0) {
        float T = 0.f;
        #pragma unroll
        for (int p = 0; p < 32; ++p) T += ptot[b * 32 + p];
        float cmean = 2.0f * T / (float)NN
                    - 2.0f * s2 / ((float)NN * (float)NN) + 1e-8f;
        scale[b] = -1.0f / (cmean * EPS);
    }
}

// ---------------------------------------------------------------- init
__global__ void init_vw(float* __restrict__ v, float* __restrict__ outW) {
    const int i = blockIdx.x * 256 + threadIdx.x;
    v[i]    = 1.0f;
    outW[i] = 1.0f / (float)NN;
}

// ---------------------------------------------------------------- build_K
// K8[b,n,m] = e4m3( KSCALE * exp(scale*(sq[n]+sq[m]-2*gram)) ), diag stored 0.
// Gram via mfma_f32_32x32x16_bf16; operands loaded straight from row-major Xbf.
__global__ __launch_bounds__(256) void build_K(const unsigned short* __restrict__ Xbf,
                                               const float* __restrict__ sq,
                                               const float* __restrict__ scale,
                                               unsigned char* __restrict__ K) {
    const int b = blockIdx.z, nt = blockIdx.y, mt = blockIdx.x;
    const int t = threadIdx.x, w = t >> 6;
    const int lane = t & 63, l31 = lane & 31, lh = lane >> 5;
    const int wr = w >> 1, wc = w & 1;            // 32x32 quadrant of 64x64 tile
    const unsigned short* Xb = Xbf + (size_t)b * NN * DD;
    const int n_row = nt * 64 + wr * 32 + l31;    // A: lane holds row l31
    const int m_row = mt * 64 + wc * 32 + l31;    // B: lane holds col l31
    bf16x8 af[4], bf[4];
    #pragma unroll
    for (int s = 0; s < 4; ++s) {                 // k = s*16 + lh*8 + (0..7)
        af[s] = *(const bf16x8*)(Xb + (size_t)n_row * DD + s * 16 + lh * 8);
        bf[s] = *(const bf16x8*)(Xb + (size_t)m_row * DD + s * 16 + lh * 8);
    }
    f32x16 acc = {};
    #pragma unroll
    for (int s = 0; s < 4; ++s)
        acc = __builtin_amdgcn_mfma_f32_32x32x16_bf16(af[s], bf[s], acc, 0, 0, 0);
    // C/D: col = l31, row = (r&3) + 8*(r>>2) + 4*lh   [m74/m101 verified]
    const float sc = scale[b];
    const float* sqb = sq + b * NN;
    const int gm = mt * 64 + wc * 32 + l31;
    const float sqm = sqb[gm];
    unsigned char* Kb = K + (size_t)b * NN * NN;
    #pragma unroll
    for (int r = 0; r < 16; ++r) {
        const int row = (r & 3) + 8 * (r >> 2) + 4 * lh;
        const int gn = nt * 64 + wr * 32 + row;
        float val = KSCALE * __expf(sc * (sqb[gn] + sqm - 2.0f * acc[r]));
        Kb[(size_t)gn * NN + gm] = (gn == gm) ? 0 : f32_to_e4m3(val);
    }
}

// ---------------------------------------------------------------- sink_pass
// MODE 0: u[n] = (w[n]+1e-16) / ( sum_m K8[n,m]*v[m] + KSCALE*v[n] )
// MODE 1: v[m] = (1/N)        / ( sum_n K8[m,n]*u[n] + KSCALE*u[m] )
template <int MODE>
__global__ __launch_bounds__(256) void sink_pass(const unsigned char* __restrict__ K,
                                                 const float* __restrict__ vin,
                                                 const float* __restrict__ wts,
                                                 float* __restrict__ out) {
    const int row  = blockIdx.x * 4 + (threadIdx.x >> 6);
    const int lane = threadIdx.x & 63;
    const unsigned char* Kr = K + (size_t)row * NN;
    const float* vb = vin + (size_t)(row >> 11) * NN;
    float acc = 0.f;
    #pragma unroll
    for (int it = 0; it < NN / 512; ++it) {
        const int m = (lane << 3) + (it << 9);
        uint2 k8 = *(const uint2*)(Kr + m);
        float kf[8];
        fp8x8_to_f32(k8.x, k8.y, kf);
        float4 va = *(const float4*)(vb + m);
        float4 vc = *(const float4*)(vb + m + 4);
        acc += kf[0] * va.x + kf[1] * va.y + kf[2] * va.z + kf[3] * va.w
             + kf[4] * vc.x + kf[5] * vc.y + kf[6] * vc.z + kf[7] * vc.w;
    }
    #pragma unroll
    for (int off = 32; off > 0; off >>= 1) acc += __shfl_down(acc, off);
    if (lane == 0) {
        const float num = (MODE == 0) ? (wts[row] + 1e-16f) : (1.0f / (float)NN);
        out[row] = num / (acc + KSCALE * vb[row & (NN - 1)]);
    }
}

// ---------------------------------------------------------------- out_gemm
// Partial: pbuf[nc,b,m,d] = sum_{n in chunk} u[n]*K8[m,n]*x[n,d]  (diag excluded)
__global__ __launch_bounds__(256) void out_gemm(const unsigned char* __restrict__ K,
                                                const float* __restrict__ X,
                                                const float* __restrict__ u,
                                                float* __restrict__ pbuf) {
    __shared__ float Ps[64][68];
    __shared__ float Xs[64][68];
    const int b = blockIdx.z, nc = blockIdx.y, mt = blockIdx.x;
    const int t = threadIdx.x;
    const int tr = (t >> 4) << 2;
    const int tc = (t & 15) << 2;
    const float* ub = u + (size_t)b * NN;
    const float* Xb = X + (size_t)b * NN * DD;
    const unsigned char* Kb = K + ((size_t)b * NN + mt * 64) * NN;
    float acc[4][4] = {};
    for (int st = 0; st < (NN / NC) / 64; ++st) {
        const int n0 = nc * (NN / NC) + st * 64;
        __syncthreads();
        {   // K tile 64x64 fp8: one uint4 (16 fp8) per thread
            const int row = t >> 2;
            const int c16 = (t & 3) << 4;
            uint4 kk = *(const uint4*)(Kb + (size_t)row * NN + n0 + c16);
            float kf[16];
            fp8x8_to_f32(kk.x, kk.y, kf);
            fp8x8_to_f32(kk.z, kk.w, kf + 8);
            #pragma unroll
            for (int j = 0; j < 16; j += 4) {
                float4 uu = *(const float4*)(ub + n0 + c16 + j);
                Ps[row][c16 + j + 0] = kf[j + 0] * uu.x;
                Ps[row][c16 + j + 1] = kf[j + 1] * uu.y;
                Ps[row][c16 + j + 2] = kf[j + 2] * uu.z;
                Ps[row][c16 + j + 3] = kf[j + 3] * uu.w;
            }
        }
        #pragma unroll
        for (int i = 0; i < 4; ++i) {           // X tile 64x64 fp32
            int f   = t + i * 256;
            int row = f >> 4;
            int c4  = (f & 15) << 2;
            *(float4*)&Xs[row][c4] =
                *(const float4*)(Xb + (size_t)(n0 + row) * DD + c4);
        }
        __syncthreads();
        #pragma unroll
        for (int c = 0; c < 64; c += 4) {
            float a[4][4], x[4][4];
            #pragma unroll
            for (int r = 0; r < 4; ++r)
                *(float4*)a[r] = *(const float4*)&Ps[tr + r][c];
            #pragma unroll
            for (int cc = 0; cc < 4; ++cc)
                *(float4*)x[cc] = *(const float4*)&Xs[c + cc][tc];
            #pragma unroll
            for (int r = 0; r < 4; ++r)
                #pragma unroll
                for (int cc = 0; cc < 4; ++cc)
                    #pragma unroll
                    for (int j = 0; j < 4; ++j)
                        acc[r][j] += a[r][cc] * x[cc][j];
        }
    }
    float* pb = pbuf + (size_t)nc * BB * NN * DD;
    #pragma unroll
    for (int r = 0; r < 4; ++r) {
        const int gm = mt * 64 + tr + r;
        *(float4*)(pb + ((size_t)b * NN + gm) * DD + tc) = *(float4*)acc[r];
    }
}

// ---------------------------------------------------------------- out_reduce
// out[b,m,d] = N * v[b,m] * ( sum_nc pbuf[nc,b,m,d] + KSCALE*u[b,m]*x[b,m,d] )
__global__ __launch_bounds__(256) void out_reduce(const float* __restrict__ pbuf,
                                                  const float* __restrict__ u,
                                                  const float* __restrict__ v,
                                                  const float* __restrict__ X,
                                                  float* __restrict__ outP) {
    const int idx = blockIdx.x * 256 + threadIdx.x;   // per float4
    const int d4 = idx & (DD / 4 - 1);
    const int bm = idx >> 4;                           // b*NN + m
    float4 s = make_float4(0.f, 0.f, 0.f, 0.f);
    #pragma unroll
    for (int nc = 0; nc < NC; ++nc) {
        float4 p = *(const float4*)(pbuf + (size_t)nc * BB * NN * DD
                                    + (size_t)bm * DD + d4 * 4);
        s.x += p.x; s.y += p.y; s.z += p.z; s.w += p.w;
    }
    const float um = KSCALE * u[bm];
    float4 xx = *(const float4*)(X + (size_t)bm * DD + d4 * 4);
    s.x += um * xx.x; s.y += um * xx.y; s.z += um * xx.z; s.w += um * xx.w;
    const float vr = (float)NN * v[bm];
    *(float4*)(outP + (size_t)bm * DD + d4 * 4) =
        make_float4(vr * s.x, vr * s.y, vr * s.z, vr * s.w);
}

// ---------------------------------------------------------------- launch
extern "C" void kernel_launch(void* const* d_in, const int* in_sizes, int n_in,
                              void* d_out, int out_size, void* d_ws, size_t ws_size,
                              hipStream_t stream) {
    const float* X = (const float*)d_in[0];   // particles [B,N,D]
    const float* W = (const float*)d_in[1];   // weights   [B,N]
    float* outP = (float*)d_out;                       // [B,N,D]
    float* outW = outP + (size_t)BB * NN * DD;         // [B,N]

    float* ws = (float*)d_ws;
    const size_t nfloats = (size_t)BB * NN          // sq
                         + 16                       // scale
                         + 2 * (size_t)BB * NN      // u, v
                         + (size_t)BB * 32 * 64 + BB * 32   // pcol, ptot
                         + (size_t)NC * BB * NN * DD;       // pbuf
    const size_t need = nfloats * 4
                      + (size_t)BB * NN * DD * 2    // Xbf
                      + (size_t)BB * NN * NN;       // K fp8
    if (ws_size < need) return;

    float* sq    = ws;
    float* scale = sq + (size_t)BB * NN;
    float* u     = scale + 16;
    float* v     = u + (size_t)BB * NN;
    float* pcol  = v + (size_t)BB * NN;
    float* ptot  = pcol + (size_t)BB * 32 * 64;
    float* pbuf  = ptot + BB * 32;
    unsigned short* Xbf = (unsigned short*)(pbuf + (size_t)NC * BB * NN * DD);
    unsigned char*  K   = (unsigned char*)(Xbf + (size_t)BB * NN * DD);

    stats1<<<dim3(BB * 32), 256, 0, stream>>>(X, Xbf, sq, pcol, ptot);
    stats2<<<dim3(BB), 64, 0, stream>>>(pcol, ptot, scale);
    init_vw<<<dim3(BB * NN / 256), 256, 0, stream>>>(v, outW);
    build_K<<<dim3(NN / 64, NN / 64, BB), 256, 0, stream>>>(Xbf, sq, scale, K);
    for (int i = 0; i < ITERS; ++i) {
        sink_pass<0><<<dim3(BB * NN / 4), 256, 0, stream>>>(K, v, W, u);
        sink_pass<1><<<dim3(BB * NN / 4), 256, 0, stream>>>(K, u, W, v);
    }
    out_gemm<<<dim3(NN / 64, NC, BB), 256, 0, stream>>>(K, X, u, pbuf);
    out_reduce<<<dim3(BB * NN * DD / 4 / 256), 256, 0, stream>>>(pbuf, u, v, X, outP);
}

// Round 6
// 224.831 us; speedup vs baseline: 2.9409x; 1.2846x over previous
//
#include <hip/hip_runtime.h>

#define BB 8
#define NN 2048
#define DD 64
#define NC 4            // split-K chunks for out_gemm
constexpr float EPS = 0.1f;
constexpr int ITERS = 10;
constexpr float KSCALE = 4096.0f;   // off-diag fp8 scale; diag handled analytically

typedef short bf16x8 __attribute__((ext_vector_type(8)));
typedef float f32x16 __attribute__((ext_vector_type(16)));
typedef float f32x2  __attribute__((ext_vector_type(2)));

// ---------------------------------------------------------------- fp8 helpers
__device__ inline float e4m3_to_f32_manual(unsigned int b) {
    unsigned int e = (b >> 3) & 15u, m = b & 7u;
    float v;
    if (e == 0) v = (float)m * 0.001953125f;              // m * 2^-9
    else        v = __uint_as_float(((e + 120u) << 23) | (m << 20));
    return (b & 0x80u) ? -v : v;
}

template <bool HI>
__device__ inline f32x2 cvt2_fp8(unsigned int w) {
#if __has_builtin(__builtin_amdgcn_cvt_pk_f32_fp8)
    return __builtin_amdgcn_cvt_pk_f32_fp8(w, HI);
#else
    f32x2 r; unsigned int s = HI ? (w >> 16) : w;
    r[0] = e4m3_to_f32_manual(s & 255u);
    r[1] = e4m3_to_f32_manual((s >> 8) & 255u);
    return r;
#endif
}

__device__ inline unsigned char f32_to_e4m3(float f) {   // f in [0, 448]
#if __has_builtin(__builtin_amdgcn_cvt_pk_fp8_f32)
    return (unsigned char)(__builtin_amdgcn_cvt_pk_fp8_f32(f, f, 0, false) & 0xFF);
#else
    if (!(f > 0.f)) return 0;
    if (f >= 448.f) return 0x7E;
    int e; float m = frexpf(f, &e);            // f = m*2^e, m in [0.5,1)
    if (e >= -5) {                              // normal: f >= 2^-6
        int mant = (int)roundf(m * 16.f) - 8;   // 0..8
        int ef = e + 6;
        if (mant == 8) { mant = 0; ef += 1; }
        if (ef >= 16) return 0x7E;
        return (unsigned char)((ef << 3) | mant);
    }
    int mant = (int)roundf(f * 512.f);          // subnormal
    if (mant >= 8) return 0x08;
    return (unsigned char)mant;
#endif
}

__device__ inline unsigned short f2bf_rne(float f) {
    unsigned int u = __float_as_uint(f);
    u += 0x7FFFu + ((u >> 16) & 1u);
    return (unsigned short)(u >> 16);
}

// ---------------------------------------------------------------- stats1
// Rounds X to bf16 (RNE), writes Xbf; sq/colsums computed from ROUNDED values
// so that the MFMA gram diagonal satisfies C_nn ~= 0 exactly.
__global__ __launch_bounds__(256) void stats1(const float* __restrict__ X,
                                              unsigned short* __restrict__ Xbf,
                                              float* __restrict__ sq,
                                              float* __restrict__ pcol,
                                              float* __restrict__ ptot) {
    const int blk = blockIdx.x;          // 0 .. BB*32-1
    const int b   = blk >> 5;
    const int r0  = (blk & 31) * 64;
    const int t = threadIdx.x, w = t >> 6, lane = t & 63;
    const float* Xb = X + (size_t)b * NN * DD;
    unsigned short* Xbfb = Xbf + (size_t)b * NN * DD;
    float cs = 0.f, sqtot = 0.f;
    #pragma unroll
    for (int i = w; i < 64; i += 4) {
        const int row = r0 + i;
        float x = Xb[(size_t)row * DD + lane];
        unsigned short hb = f2bf_rne(x);
        Xbfb[(size_t)row * DD + lane] = hb;
        float xr = __uint_as_float((unsigned int)hb << 16);
        cs += xr;
        float s = xr * xr;
        #pragma unroll
        for (int off = 32; off > 0; off >>= 1) s += __shfl_down(s, off);
        if (lane == 0) { sq[b * NN + row] = s; sqtot += s; }
    }
    __shared__ float colS[4][64];
    __shared__ float totS[4];
    colS[w][lane] = cs;
    if (lane == 0) totS[w] = sqtot;
    __syncthreads();
    if (t < 64)
        pcol[blk * 64 + t] = colS[0][t] + colS[1][t] + colS[2][t] + colS[3][t];
    if (t == 0)
        ptot[blk] = totS[0] + totS[1] + totS[2] + totS[3];
}

// ---------------------------------------------------------------- stats2
__global__ void stats2(const float* __restrict__ pcol,
                       const float* __restrict__ ptot,
                       float* __restrict__ scale) {
    const int b = blockIdx.x, t = threadIdx.x;   // 64 threads
    float c = 0.f;
    #pragma unroll
    for (int p = 0; p < 32; ++p) c += pcol[(b * 32 + p) * 64 + t];
    float s2 = c * c;
    #pragma unroll
    for (int off = 32; off > 0; off >>= 1) s2 += __shfl_down(s2, off);
    if (t == 0) {
        float T = 0.f;
        #pragma unroll
        for (int p = 0; p < 32; ++p) T += ptot[b * 32 + p];
        float cmean = 2.0f * T / (float)NN
                    - 2.0f * s2 / ((float)NN * (float)NN) + 1e-8f;
        scale[b] = -1.0f / (cmean * EPS);
    }
}

// ---------------------------------------------------------------- init
__global__ void init_vw(float* __restrict__ v, float* __restrict__ outW) {
    const int i = blockIdx.x * 256 + threadIdx.x;
    v[i]    = 1.0f;
    outW[i] = 1.0f / (float)NN;
}

// ---------------------------------------------------------------- build_K
// K8[b,n,m] = e4m3( KSCALE * exp(scale*(sq[n]+sq[m]-2*gram)) ), diag stored 0.
__global__ __launch_bounds__(256) void build_K(const unsigned short* __restrict__ Xbf,
                                               const float* __restrict__ sq,
                                               const float* __restrict__ scale,
                                               unsigned char* __restrict__ K) {
    const int b = blockIdx.z, nt = blockIdx.y, mt = blockIdx.x;
    const int t = threadIdx.x, w = t >> 6;
    const int lane = t & 63, l31 = lane & 31, lh = lane >> 5;
    const int wr = w >> 1, wc = w & 1;            // 32x32 quadrant of 64x64 tile
    const unsigned short* Xb = Xbf + (size_t)b * NN * DD;
    const int n_row = nt * 64 + wr * 32 + l31;    // A: lane holds row l31
    const int m_row = mt * 64 + wc * 32 + l31;    // B: lane holds col l31
    bf16x8 af[4], bf[4];
    #pragma unroll
    for (int s = 0; s < 4; ++s) {                 // k = s*16 + lh*8 + (0..7)
        af[s] = *(const bf16x8*)(Xb + (size_t)n_row * DD + s * 16 + lh * 8);
        bf[s] = *(const bf16x8*)(Xb + (size_t)m_row * DD + s * 16 + lh * 8);
    }
    f32x16 acc = {};
    #pragma unroll
    for (int s = 0; s < 4; ++s)
        acc = __builtin_amdgcn_mfma_f32_32x32x16_bf16(af[s], bf[s], acc, 0, 0, 0);
    // C/D: col = l31, row = (r&3) + 8*(r>>2) + 4*lh   [m74/m101 verified]
    const float sc = scale[b];
    const float* sqb = sq + b * NN;
    const int gm = mt * 64 + wc * 32 + l31;
    const float sqm = sqb[gm];
    unsigned char* Kb = K + (size_t)b * NN * NN;
    #pragma unroll
    for (int r = 0; r < 16; ++r) {
        const int row = (r & 3) + 8 * (r >> 2) + 4 * lh;
        const int gn = nt * 64 + wr * 32 + row;
        float val = KSCALE * __expf(sc * (sqb[gn] + sqm - 2.0f * acc[r]));
        Kb[(size_t)gn * NN + gm] = (gn == gm) ? 0 : f32_to_e4m3(val);
    }
}

// ---------------------------------------------------------------- sink_pass
// MODE 0: u[n] = (w[n]+1e-16) / ( sum_m K8[n,m]*v[m] + KSCALE*v[n] )
// MODE 1: v[m] = (1/N)        / ( sum_n K8[m,n]*u[n] + KSCALE*u[m] )
// v staged in LDS (8 KB) once per block; K streamed as per-lane dwords.
template <int MODE>
__global__ __launch_bounds__(256) void sink_pass(const unsigned char* __restrict__ K,
                                                 const float* __restrict__ vin,
                                                 const float* __restrict__ wts,
                                                 float* __restrict__ out) {
    __shared__ float vs[NN];
    const int t = threadIdx.x;
    const int row  = blockIdx.x * 4 + (t >> 6);
    const int lane = t & 63;
    const float* vb = vin + (size_t)(row >> 11) * NN;
    #pragma unroll
    for (int s = 0; s < 2; ++s)
        *(float4*)&vs[(t + s * 256) * 4] = *(const float4*)&vb[(t + s * 256) * 4];
    __syncthreads();
    const unsigned char* Kr = K + (size_t)row * NN;
    float acc = 0.f;
    #pragma unroll
    for (int it = 0; it < NN / 256; ++it) {
        const int m = it * 256 + lane * 4;
        const unsigned int k4 = *(const unsigned int*)(Kr + m);
        f32x2 plo = cvt2_fp8<false>(k4);
        f32x2 phi = cvt2_fp8<true>(k4);
        float4 vv = *(const float4*)&vs[m];
        acc += plo[0] * vv.x + plo[1] * vv.y + phi[0] * vv.z + phi[1] * vv.w;
    }
    #pragma unroll
    for (int off = 32; off > 0; off >>= 1) acc += __shfl_down(acc, off);
    if (lane == 0) {
        const float num = (MODE == 0) ? (wts[row] + 1e-16f) : (1.0f / (float)NN);
        out[row] = num / (acc + KSCALE * vs[row & (NN - 1)]);
    }
}

// ---------------------------------------------------------------- yprep
// Yt[b][d][n] = bf16( u[b][n] * X[b][n][d] )   (transposed for MFMA B-frags)
__global__ __launch_bounds__(256) void yprep(const float* __restrict__ X,
                                             const float* __restrict__ u,
                                             unsigned short* __restrict__ Yt) {
    __shared__ float T[64][65];
    const int b = blockIdx.y, nt = blockIdx.x, t = threadIdx.x;
    const int nl = t >> 2, c0 = (t & 3) << 4;
    const float* Xb = X + ((size_t)b * NN + nt * 64) * DD;
    const float uu = u[(size_t)b * NN + nt * 64 + nl];
    #pragma unroll
    for (int j = 0; j < 4; ++j) {
        float4 x = *(const float4*)(Xb + (size_t)nl * DD + c0 + j * 4);
        T[c0 + j * 4 + 0][nl] = uu * x.x;
        T[c0 + j * 4 + 1][nl] = uu * x.y;
        T[c0 + j * 4 + 2][nl] = uu * x.z;
        T[c0 + j * 4 + 3][nl] = uu * x.w;
    }
    __syncthreads();
    const int d = t >> 2, n0 = (t & 3) << 4;
    unsigned short* Yr = Yt + ((size_t)b * DD + d) * NN + nt * 64 + n0;
    unsigned int ow[8];
    #pragma unroll
    for (int j = 0; j < 8; ++j) {
        unsigned int lo = f2bf_rne(T[d][n0 + 2 * j]);
        unsigned int hi = f2bf_rne(T[d][n0 + 2 * j + 1]);
        ow[j] = lo | (hi << 16);
    }
    *(uint4*)(Yr)     = make_uint4(ow[0], ow[1], ow[2], ow[3]);
    *(uint4*)(Yr + 8) = make_uint4(ow[4], ow[5], ow[6], ow[7]);
}

// ---------------------------------------------------------------- out_gemm
// pbuf[nc,b,m,d] = sum_{n in chunk} K8[m,n]*u[n]*x[n,d]  via bf16 MFMA.
// A = fp8 K decoded to bf16 (exact), B = Yt fragments (contiguous loads).
__global__ __launch_bounds__(256) void out_gemm(const unsigned char* __restrict__ K,
                                                const unsigned short* __restrict__ Yt,
                                                float* __restrict__ pbuf) {
    const int b = blockIdx.z, nc = blockIdx.y, mt = blockIdx.x;
    const int t = threadIdx.x, w = t >> 6, lane = t & 63;
    const int l31 = lane & 31, lh = lane >> 5;
    const int wr = w >> 1, wc = w & 1;
    const unsigned char*  Kr = K  + ((size_t)b * NN + mt * 64 + wr * 32 + l31) * NN;
    const unsigned short* Yr = Yt + ((size_t)b * DD + wc * 32 + l31) * NN;
    f32x16 acc = {};
    #pragma unroll 4
    for (int st = 0; st < (NN / NC) / 16; ++st) {
        const int n = nc * (NN / NC) + st * 16 + lh * 8;
        const uint2 k8 = *(const uint2*)(Kr + n);
        f32x2 p0 = cvt2_fp8<false>(k8.x);
        f32x2 p1 = cvt2_fp8<true>(k8.x);
        f32x2 p2 = cvt2_fp8<false>(k8.y);
        f32x2 p3 = cvt2_fp8<true>(k8.y);
        union { unsigned int u4[4]; bf16x8 v8; } av;
        av.u4[0] = __builtin_amdgcn_perm(__float_as_uint(p0[1]), __float_as_uint(p0[0]), 0x07060302);
        av.u4[1] = __builtin_amdgcn_perm(__float_as_uint(p1[1]), __float_as_uint(p1[0]), 0x07060302);
        av.u4[2] = __builtin_amdgcn_perm(__float_as_uint(p2[1]), __float_as_uint(p2[0]), 0x07060302);
        av.u4[3] = __builtin_amdgcn_perm(__float_as_uint(p3[1]), __float_as_uint(p3[0]), 0x07060302);
        bf16x8 bv = *(const bf16x8*)(Yr + n);
        acc = __builtin_amdgcn_mfma_f32_32x32x16_bf16(av.v8, bv, acc, 0, 0, 0);
    }
    float* pb = pbuf + (((size_t)nc * BB + b) * NN + mt * 64 + wr * 32) * DD
              + wc * 32 + l31;
    #pragma unroll
    for (int r = 0; r < 16; ++r) {
        const int row = (r & 3) + 8 * (r >> 2) + 4 * lh;
        pb[(size_t)row * DD] = acc[r];
    }
}

// ---------------------------------------------------------------- out_reduce
// out[b,m,d] = N * v[b,m] * ( sum_nc pbuf[nc,b,m,d] + KSCALE*u[b,m]*x[b,m,d] )
__global__ __launch_bounds__(256) void out_reduce(const float* __restrict__ pbuf,
                                                  const float* __restrict__ u,
                                                  const float* __restrict__ v,
                                                  const float* __restrict__ X,
                                                  float* __restrict__ outP) {
    const int idx = blockIdx.x * 256 + threadIdx.x;   // per float4
    const int d4 = idx & (DD / 4 - 1);
    const int bm = idx >> 4;                           // b*NN + m
    float4 s = make_float4(0.f, 0.f, 0.f, 0.f);
    #pragma unroll
    for (int nc = 0; nc < NC; ++nc) {
        float4 p = *(const float4*)(pbuf + (size_t)nc * BB * NN * DD
                                    + (size_t)bm * DD + d4 * 4);
        s.x += p.x; s.y += p.y; s.z += p.z; s.w += p.w;
    }
    const float um = KSCALE * u[bm];
    float4 xx = *(const float4*)(X + (size_t)bm * DD + d4 * 4);
    s.x += um * xx.x; s.y += um * xx.y; s.z += um * xx.z; s.w += um * xx.w;
    const float vr = (float)NN * v[bm];
    *(float4*)(outP + (size_t)bm * DD + d4 * 4) =
        make_float4(vr * s.x, vr * s.y, vr * s.z, vr * s.w);
}

// ---------------------------------------------------------------- launch
extern "C" void kernel_launch(void* const* d_in, const int* in_sizes, int n_in,
                              void* d_out, int out_size, void* d_ws, size_t ws_size,
                              hipStream_t stream) {
    const float* X = (const float*)d_in[0];   // particles [B,N,D]
    const float* W = (const float*)d_in[1];   // weights   [B,N]
    float* outP = (float*)d_out;                       // [B,N,D]
    float* outW = outP + (size_t)BB * NN * DD;         // [B,N]

    float* ws = (float*)d_ws;
    const size_t nfloats = (size_t)BB * NN          // sq
                         + 16                       // scale
                         + 2 * (size_t)BB * NN      // u, v
                         + (size_t)BB * 32 * 64 + BB * 32   // pcol, ptot
                         + (size_t)NC * BB * NN * DD;       // pbuf
    const size_t need = nfloats * 4
                      + (size_t)BB * NN * DD * 2    // Xbf
                      + (size_t)BB * DD * NN * 2    // Yt
                      + (size_t)BB * NN * NN;       // K fp8
    if (ws_size < need) return;

    float* sq    = ws;
    float* scale = sq + (size_t)BB * NN;
    float* u     = scale + 16;
    float* v     = u + (size_t)BB * NN;
    float* pcol  = v + (size_t)BB * NN;
    float* ptot  = pcol + (size_t)BB * 32 * 64;
    float* pbuf  = ptot + BB * 32;
    unsigned short* Xbf = (unsigned short*)(pbuf + (size_t)NC * BB * NN * DD);
    unsigned short* Yt  = Xbf + (size_t)BB * NN * DD;
    unsigned char*  K   = (unsigned char*)(Yt + (size_t)BB * DD * NN);

    stats1<<<dim3(BB * 32), 256, 0, stream>>>(X, Xbf, sq, pcol, ptot);
    stats2<<<dim3(BB), 64, 0, stream>>>(pcol, ptot, scale);
    init_vw<<<dim3(BB * NN / 256), 256, 0, stream>>>(v, outW);
    build_K<<<dim3(NN / 64, NN / 64, BB), 256, 0, stream>>>(Xbf, sq, scale, K);
    for (int i = 0; i < ITERS; ++i) {
        sink_pass<0><<<dim3(BB * NN / 4), 256, 0, stream>>>(K, v, W, u);
        sink_pass<1><<<dim3(BB * NN / 4), 256, 0, stream>>>(K, u, W, v);
    }
    yprep<<<dim3(NN / 64, BB), 256, 0, stream>>>(X, u, Yt);
    out_gemm<<<dim3(NN / 64, NC, BB), 256, 0, stream>>>(K, Yt, pbuf);
    out_reduce<<<dim3(BB * NN * DD / 4 / 256), 256, 0, stream>>>(pbuf, u, v, X, outP);
}

// Round 7
// 204.686 us; speedup vs baseline: 3.2303x; 1.0984x over previous
//
#include <hip/hip_runtime.h>

#define BB 8
#define NN 2048
#define DD 64
#define NC 4            // split-K chunks for out_gemm
constexpr float EPS = 0.1f;
constexpr int ITERS = 10;
constexpr float KSCALE = 4096.0f;   // off-diag fp8 scale; diag handled analytically

typedef short bf16x8 __attribute__((ext_vector_type(8)));
typedef float f32x16 __attribute__((ext_vector_type(16)));
typedef float f32x2  __attribute__((ext_vector_type(2)));

// ---------------------------------------------------------------- fp8 helpers
__device__ inline float e4m3_to_f32_manual(unsigned int b) {
    unsigned int e = (b >> 3) & 15u, m = b & 7u;
    float v;
    if (e == 0) v = (float)m * 0.001953125f;              // m * 2^-9
    else        v = __uint_as_float(((e + 120u) << 23) | (m << 20));
    return (b & 0x80u) ? -v : v;
}

template <bool HI>
__device__ inline f32x2 cvt2_fp8(unsigned int w) {
#if __has_builtin(__builtin_amdgcn_cvt_pk_f32_fp8)
    return __builtin_amdgcn_cvt_pk_f32_fp8(w, HI);
#else
    f32x2 r; unsigned int s = HI ? (w >> 16) : w;
    r[0] = e4m3_to_f32_manual(s & 255u);
    r[1] = e4m3_to_f32_manual((s >> 8) & 255u);
    return r;
#endif
}

__device__ inline unsigned char f32_to_e4m3(float f) {   // f in [0, 448]
#if __has_builtin(__builtin_amdgcn_cvt_pk_fp8_f32)
    return (unsigned char)(__builtin_amdgcn_cvt_pk_fp8_f32(f, f, 0, false) & 0xFF);
#else
    if (!(f > 0.f)) return 0;
    if (f >= 448.f) return 0x7E;
    int e; float m = frexpf(f, &e);            // f = m*2^e, m in [0.5,1)
    if (e >= -5) {                              // normal: f >= 2^-6
        int mant = (int)roundf(m * 16.f) - 8;   // 0..8
        int ef = e + 6;
        if (mant == 8) { mant = 0; ef += 1; }
        if (ef >= 16) return 0x7E;
        return (unsigned char)((ef << 3) | mant);
    }
    int mant = (int)roundf(f * 512.f);          // subnormal
    if (mant >= 8) return 0x08;
    return (unsigned char)mant;
#endif
}

__device__ inline unsigned int pack4_e4m3(float a, float b, float c, float d) {
#if __has_builtin(__builtin_amdgcn_cvt_pk_fp8_f32)
    unsigned int w = 0;
    w = (unsigned int)__builtin_amdgcn_cvt_pk_fp8_f32(a, b, (int)w, false);
    w = (unsigned int)__builtin_amdgcn_cvt_pk_fp8_f32(c, d, (int)w, true);
    return w;
#else
    return (unsigned int)f32_to_e4m3(a) | ((unsigned int)f32_to_e4m3(b) << 8)
         | ((unsigned int)f32_to_e4m3(c) << 16) | ((unsigned int)f32_to_e4m3(d) << 24);
#endif
}

__device__ inline unsigned short f2bf_rne(float f) {
    unsigned int u = __float_as_uint(f);
    u += 0x7FFFu + ((u >> 16) & 1u);
    return (unsigned short)(u >> 16);
}

// ---------------------------------------------------------------- stats1
// b = blk&7 so batch b's X/sq traffic lands on XCD b (consistent everywhere).
__global__ __launch_bounds__(256) void stats1(const float* __restrict__ X,
                                              unsigned short* __restrict__ Xbf,
                                              float* __restrict__ sq,
                                              float* __restrict__ pcol,
                                              float* __restrict__ ptot) {
    const int blk = blockIdx.x;          // 0 .. BB*32-1
    const int b   = blk & 7;
    const int ch  = blk >> 3;            // 0..31
    const int r0  = ch * 64;
    const int t = threadIdx.x, w = t >> 6, lane = t & 63;
    const float* Xb = X + (size_t)b * NN * DD;
    unsigned short* Xbfb = Xbf + (size_t)b * NN * DD;
    float cs = 0.f, sqtot = 0.f;
    #pragma unroll
    for (int i = w; i < 64; i += 4) {
        const int row = r0 + i;
        float x = Xb[(size_t)row * DD + lane];
        unsigned short hb = f2bf_rne(x);
        Xbfb[(size_t)row * DD + lane] = hb;
        float xr = __uint_as_float((unsigned int)hb << 16);
        cs += xr;
        float s = xr * xr;
        #pragma unroll
        for (int off = 32; off > 0; off >>= 1) s += __shfl_down(s, off);
        if (lane == 0) { sq[b * NN + row] = s; sqtot += s; }
    }
    __shared__ float colS[4][64];
    __shared__ float totS[4];
    colS[w][lane] = cs;
    if (lane == 0) totS[w] = sqtot;
    __syncthreads();
    if (t < 64)
        pcol[(b * 32 + ch) * 64 + t] = colS[0][t] + colS[1][t] + colS[2][t] + colS[3][t];
    if (t == 0)
        ptot[b * 32 + ch] = totS[0] + totS[1] + totS[2] + totS[3];
}

// ---------------------------------------------------------------- stats2
__global__ void stats2(const float* __restrict__ pcol,
                       const float* __restrict__ ptot,
                       float* __restrict__ scale) {
    const int b = blockIdx.x, t = threadIdx.x;   // 64 threads
    float c = 0.f;
    #pragma unroll
    for (int p = 0; p < 32; ++p) c += pcol[(b * 32 + p) * 64 + t];
    float s2 = c * c;
    #pragma unroll
    for (int off = 32; off > 0; off >>= 1) s2 += __shfl_down(s2, off);
    if (t == 0) {
        float T = 0.f;
        #pragma unroll
        for (int p = 0; p < 32; ++p) T += ptot[b * 32 + p];
        float cmean = 2.0f * T / (float)NN
                    - 2.0f * s2 / ((float)NN * (float)NN) + 1e-8f;
        scale[b] = -1.0f / (cmean * EPS);
    }
}

// ---------------------------------------------------------------- init
__global__ void init_vw(float* __restrict__ v, float* __restrict__ outW) {
    const int i = blockIdx.x * 256 + threadIdx.x;
    v[i]    = 1.0f;
    outW[i] = 1.0f / (float)NN;
}

// ---------------------------------------------------------------- build_K
// K8[b,n,m] = e4m3( KSCALE * exp(scale*(sq[n]+sq[m]-2*gram)) ), diag stored 0.
// 1D grid, b = bid&7 -> batch b's K writes land in XCD b's L2 and STAY there
// for the 20 sink passes + out_gemm (identical swizzle).
// Epilogue: LDS f32 tile -> packed fp8 uint4 coalesced stores.
__global__ __launch_bounds__(256) void build_K(const unsigned short* __restrict__ Xbf,
                                               const float* __restrict__ sq,
                                               const float* __restrict__ scale,
                                               unsigned char* __restrict__ K) {
    __shared__ float T[64][68];
    const int bid = blockIdx.x;                   // 0..8191
    const int b = bid & 7, tix = bid >> 3;        // tix 0..1023
    const int nt = tix & 31, mt = tix >> 5;
    const int t = threadIdx.x, w = t >> 6;
    const int lane = t & 63, l31 = lane & 31, lh = lane >> 5;
    const int wr = w >> 1, wc = w & 1;            // 32x32 quadrant of 64x64 tile
    const unsigned short* Xb = Xbf + (size_t)b * NN * DD;
    const int n_row = nt * 64 + wr * 32 + l31;    // A: lane holds row l31
    const int m_row = mt * 64 + wc * 32 + l31;    // B: lane holds col l31
    bf16x8 af[4], bf[4];
    #pragma unroll
    for (int s = 0; s < 4; ++s) {                 // k = s*16 + lh*8 + (0..7)
        af[s] = *(const bf16x8*)(Xb + (size_t)n_row * DD + s * 16 + lh * 8);
        bf[s] = *(const bf16x8*)(Xb + (size_t)m_row * DD + s * 16 + lh * 8);
    }
    f32x16 acc = {};
    #pragma unroll
    for (int s = 0; s < 4; ++s)
        acc = __builtin_amdgcn_mfma_f32_32x32x16_bf16(af[s], bf[s], acc, 0, 0, 0);
    // C/D: col = l31, row = (r&3) + 8*(r>>2) + 4*lh   [m74/m101 verified]
    const float sc = scale[b];
    const float* sqb = sq + b * NN;
    const int gm = mt * 64 + wc * 32 + l31;
    const float sqm = sqb[gm];
    #pragma unroll
    for (int r = 0; r < 16; ++r) {
        const int row = (r & 3) + 8 * (r >> 2) + 4 * lh;
        const int gn = nt * 64 + wr * 32 + row;
        float val = KSCALE * __expf(sc * (sqb[gn] + sqm - 2.0f * acc[r]));
        T[wr * 32 + row][wc * 32 + l31] = (gn == gm) ? 0.0f : val;
    }
    __syncthreads();
    // re-read row-major, pack 16 fp8/thread, one uint4 store per thread
    const int orow = t >> 2, oseg = t & 3;        // 64 rows x 4 segs of 16
    float vv[16];
    #pragma unroll
    for (int j = 0; j < 4; ++j)
        *(float4*)&vv[j * 4] = *(const float4*)&T[orow][oseg * 16 + j * 4];
    uint4 o;
    o.x = pack4_e4m3(vv[0],  vv[1],  vv[2],  vv[3]);
    o.y = pack4_e4m3(vv[4],  vv[5],  vv[6],  vv[7]);
    o.z = pack4_e4m3(vv[8],  vv[9],  vv[10], vv[11]);
    o.w = pack4_e4m3(vv[12], vv[13], vv[14], vv[15]);
    unsigned char* Kb = K + (size_t)b * NN * NN;
    *(uint4*)(Kb + (size_t)(nt * 64 + orow) * NN + mt * 64 + oseg * 16) = o;
}

// ---------------------------------------------------------------- sink_pass
// MODE 0: u[n] = (w[n]+1e-16) / ( sum_m K8[n,m]*v[m] + KSCALE*v[n] )
// MODE 1: v[m] = (1/N)        / ( sum_n K8[m,n]*u[n] + KSCALE*u[m] )
// b = bid&7: batch b's K rows + v vector stay resident in XCD b's L2
// across all 20 passes (identical grid & swizzle each launch).
template <int MODE>
__global__ __launch_bounds__(256) void sink_pass(const unsigned char* __restrict__ K,
                                                 const float* __restrict__ vin,
                                                 const float* __restrict__ wts,
                                                 float* __restrict__ out) {
    __shared__ float vs[NN];
    const int bid = blockIdx.x;                   // 0..4095
    const int b = bid & 7, j = bid >> 3;          // j 0..511
    const int t = threadIdx.x;
    const int lr = j * 4 + (t >> 6);              // local row in batch
    const int lane = t & 63;
    const float* vb = vin + (size_t)b * NN;
    #pragma unroll
    for (int s = 0; s < 2; ++s)
        *(float4*)&vs[(t + s * 256) * 4] = *(const float4*)&vb[(t + s * 256) * 4];
    __syncthreads();
    const unsigned char* Kr = K + ((size_t)b * NN + lr) * NN;
    float acc = 0.f;
    #pragma unroll
    for (int it = 0; it < NN / 256; ++it) {
        const int m = it * 256 + lane * 4;
        const unsigned int k4 = *(const unsigned int*)(Kr + m);
        f32x2 plo = cvt2_fp8<false>(k4);
        f32x2 phi = cvt2_fp8<true>(k4);
        float4 vv = *(const float4*)&vs[m];
        acc += plo[0] * vv.x + plo[1] * vv.y + phi[0] * vv.z + phi[1] * vv.w;
    }
    #pragma unroll
    for (int off = 32; off > 0; off >>= 1) acc += __shfl_down(acc, off);
    if (lane == 0) {
        const float num = (MODE == 0) ? (wts[(size_t)b * NN + lr] + 1e-16f)
                                      : (1.0f / (float)NN);
        out[(size_t)b * NN + lr] = num / (acc + KSCALE * vs[lr]);
    }
}

// ---------------------------------------------------------------- yprep
// Yt[b][d][n] = bf16( u[b][n] * X[b][n][d] )   (transposed for MFMA B-frags)
__global__ __launch_bounds__(256) void yprep(const float* __restrict__ X,
                                             const float* __restrict__ u,
                                             unsigned short* __restrict__ Yt) {
    __shared__ float T[64][65];
    const int bid = blockIdx.x;                   // 0..255
    const int b = bid & 7, nt = bid >> 3;
    const int t = threadIdx.x;
    const int nl = t >> 2, c0 = (t & 3) << 4;
    const float* Xb = X + ((size_t)b * NN + nt * 64) * DD;
    const float uu = u[(size_t)b * NN + nt * 64 + nl];
    #pragma unroll
    for (int j = 0; j < 4; ++j) {
        float4 x = *(const float4*)(Xb + (size_t)nl * DD + c0 + j * 4);
        T[c0 + j * 4 + 0][nl] = uu * x.x;
        T[c0 + j * 4 + 1][nl] = uu * x.y;
        T[c0 + j * 4 + 2][nl] = uu * x.z;
        T[c0 + j * 4 + 3][nl] = uu * x.w;
    }
    __syncthreads();
    const int d = t >> 2, n0 = (t & 3) << 4;
    unsigned short* Yr = Yt + ((size_t)b * DD + d) * NN + nt * 64 + n0;
    unsigned int ow[8];
    #pragma unroll
    for (int j = 0; j < 8; ++j) {
        unsigned int lo = f2bf_rne(T[d][n0 + 2 * j]);
        unsigned int hi = f2bf_rne(T[d][n0 + 2 * j + 1]);
        ow[j] = lo | (hi << 16);
    }
    *(uint4*)(Yr)     = make_uint4(ow[0], ow[1], ow[2], ow[3]);
    *(uint4*)(Yr + 8) = make_uint4(ow[4], ow[5], ow[6], ow[7]);
}

// ---------------------------------------------------------------- out_gemm
// pbuf[nc,b,m,d] = sum_{n in chunk} K8[m,n]*u[n]*x[n,d]  via bf16 MFMA.
// b = bid&7: K reads hit XCD b's L2 (same pinning as sink passes).
__global__ __launch_bounds__(256) void out_gemm(const unsigned char* __restrict__ K,
                                                const unsigned short* __restrict__ Yt,
                                                float* __restrict__ pbuf) {
    const int bid = blockIdx.x;                   // 0..1023
    const int b = bid & 7, tix = bid >> 3;        // tix 0..127
    const int nc = tix & (NC - 1), mt = tix >> 2; // mt 0..31
    const int t = threadIdx.x, w = t >> 6, lane = t & 63;
    const int l31 = lane & 31, lh = lane >> 5;
    const int wr = w >> 1, wc = w & 1;
    const unsigned char*  Kr = K  + ((size_t)b * NN + mt * 64 + wr * 32 + l31) * NN;
    const unsigned short* Yr = Yt + ((size_t)b * DD + wc * 32 + l31) * NN;
    f32x16 acc = {};
    #pragma unroll 4
    for (int st = 0; st < (NN / NC) / 16; ++st) {
        const int n = nc * (NN / NC) + st * 16 + lh * 8;
        const uint2 k8 = *(const uint2*)(Kr + n);
        f32x2 p0 = cvt2_fp8<false>(k8.x);
        f32x2 p1 = cvt2_fp8<true>(k8.x);
        f32x2 p2 = cvt2_fp8<false>(k8.y);
        f32x2 p3 = cvt2_fp8<true>(k8.y);
        union { unsigned int u4[4]; bf16x8 v8; } av;
        av.u4[0] = __builtin_amdgcn_perm(__float_as_uint(p0[1]), __float_as_uint(p0[0]), 0x07060302);
        av.u4[1] = __builtin_amdgcn_perm(__float_as_uint(p1[1]), __float_as_uint(p1[0]), 0x07060302);
        av.u4[2] = __builtin_amdgcn_perm(__float_as_uint(p2[1]), __float_as_uint(p2[0]), 0x07060302);
        av.u4[3] = __builtin_amdgcn_perm(__float_as_uint(p3[1]), __float_as_uint(p3[0]), 0x07060302);
        bf16x8 bv = *(const bf16x8*)(Yr + n);
        acc = __builtin_amdgcn_mfma_f32_32x32x16_bf16(av.v8, bv, acc, 0, 0, 0);
    }
    float* pb = pbuf + (((size_t)nc * BB + b) * NN + mt * 64 + wr * 32) * DD
              + wc * 32 + l31;
    #pragma unroll
    for (int r = 0; r < 16; ++r) {
        const int row = (r & 3) + 8 * (r >> 2) + 4 * lh;
        pb[(size_t)row * DD] = acc[r];
    }
}

// ---------------------------------------------------------------- out_reduce
// out[b,m,d] = N * v[b,m] * ( sum_nc pbuf[nc,b,m,d] + KSCALE*u[b,m]*x[b,m,d] )
__global__ __launch_bounds__(256) void out_reduce(const float* __restrict__ pbuf,
                                                  const float* __restrict__ u,
                                                  const float* __restrict__ v,
                                                  const float* __restrict__ X,
                                                  float* __restrict__ outP) {
    const int idx = blockIdx.x * 256 + threadIdx.x;   // per float4
    const int d4 = idx & (DD / 4 - 1);
    const int bm = idx >> 4;                           // b*NN + m
    float4 s = make_float4(0.f, 0.f, 0.f, 0.f);
    #pragma unroll
    for (int nc = 0; nc < NC; ++nc) {
        float4 p = *(const float4*)(pbuf + (size_t)nc * BB * NN * DD
                                    + (size_t)bm * DD + d4 * 4);
        s.x += p.x; s.y += p.y; s.z += p.z; s.w += p.w;
    }
    const float um = KSCALE * u[bm];
    float4 xx = *(const float4*)(X + (size_t)bm * DD + d4 * 4);
    s.x += um * xx.x; s.y += um * xx.y; s.z += um * xx.z; s.w += um * xx.w;
    const float vr = (float)NN * v[bm];
    *(float4*)(outP + (size_t)bm * DD + d4 * 4) =
        make_float4(vr * s.x, vr * s.y, vr * s.z, vr * s.w);
}

// ---------------------------------------------------------------- launch
extern "C" void kernel_launch(void* const* d_in, const int* in_sizes, int n_in,
                              void* d_out, int out_size, void* d_ws, size_t ws_size,
                              hipStream_t stream) {
    const float* X = (const float*)d_in[0];   // particles [B,N,D]
    const float* W = (const float*)d_in[1];   // weights   [B,N]
    float* outP = (float*)d_out;                       // [B,N,D]
    float* outW = outP + (size_t)BB * NN * DD;         // [B,N]

    float* ws = (float*)d_ws;
    const size_t nfloats = (size_t)BB * NN          // sq
                         + 16                       // scale
                         + 2 * (size_t)BB * NN      // u, v
                         + (size_t)BB * 32 * 64 + BB * 32   // pcol, ptot
                         + (size_t)NC * BB * NN * DD;       // pbuf
    const size_t need = nfloats * 4
                      + (size_t)BB * NN * DD * 2    // Xbf
                      + (size_t)BB * DD * NN * 2    // Yt
                      + (size_t)BB * NN * NN;       // K fp8
    if (ws_size < need) return;

    float* sq    = ws;
    float* scale = sq + (size_t)BB * NN;
    float* u     = scale + 16;
    float* v     = u + (size_t)BB * NN;
    float* pcol  = v + (size_t)BB * NN;
    float* ptot  = pcol + (size_t)BB * 32 * 64;
    float* pbuf  = ptot + BB * 32;
    unsigned short* Xbf = (unsigned short*)(pbuf + (size_t)NC * BB * NN * DD);
    unsigned short* Yt  = Xbf + (size_t)BB * NN * DD;
    unsigned char*  K   = (unsigned char*)(Yt + (size_t)BB * DD * NN);

    stats1<<<dim3(BB * 32), 256, 0, stream>>>(X, Xbf, sq, pcol, ptot);
    stats2<<<dim3(BB), 64, 0, stream>>>(pcol, ptot, scale);
    init_vw<<<dim3(BB * NN / 256), 256, 0, stream>>>(v, outW);
    build_K<<<dim3(32 * 32 * BB), 256, 0, stream>>>(Xbf, sq, scale, K);
    for (int i = 0; i < ITERS; ++i) {
        sink_pass<0><<<dim3(BB * NN / 4), 256, 0, stream>>>(K, v, W, u);
        sink_pass<1><<<dim3(BB * NN / 4), 256, 0, stream>>>(K, u, W, v);
    }
    yprep<<<dim3(BB * NN / 64), 256, 0, stream>>>(X, u, Yt);
    out_gemm<<<dim3((NN / 64) * NC * BB), 256, 0, stream>>>(K, Yt, pbuf);
    out_reduce<<<dim3(BB * NN * DD / 4 / 256), 256, 0, stream>>>(pbuf, u, v, X, outP);
}

// Round 8
// 201.509 us; speedup vs baseline: 3.2812x; 1.0158x over previous
//
#include <hip/hip_runtime.h>

#define BB 8
#define NN 2048
#define DD 64
#define NC 4            // split-K chunks for out_gemm
constexpr float EPS = 0.1f;
constexpr int ITERS = 10;
constexpr float KSCALE = 4096.0f;   // off-diag fp8 scale; diag handled analytically

typedef short bf16x8 __attribute__((ext_vector_type(8)));
typedef float f32x16 __attribute__((ext_vector_type(16)));
typedef float f32x2  __attribute__((ext_vector_type(2)));

// ---------------------------------------------------------------- fp8 helpers
__device__ inline float e4m3_to_f32_manual(unsigned int b) {
    unsigned int e = (b >> 3) & 15u, m = b & 7u;
    float v;
    if (e == 0) v = (float)m * 0.001953125f;              // m * 2^-9
    else        v = __uint_as_float(((e + 120u) << 23) | (m << 20));
    return (b & 0x80u) ? -v : v;
}

template <bool HI>
__device__ inline f32x2 cvt2_fp8(unsigned int w) {
#if __has_builtin(__builtin_amdgcn_cvt_pk_f32_fp8)
    return __builtin_amdgcn_cvt_pk_f32_fp8(w, HI);
#else
    f32x2 r; unsigned int s = HI ? (w >> 16) : w;
    r[0] = e4m3_to_f32_manual(s & 255u);
    r[1] = e4m3_to_f32_manual((s >> 8) & 255u);
    return r;
#endif
}

__device__ inline unsigned char f32_to_e4m3(float f) {   // f in [0, 448]
#if __has_builtin(__builtin_amdgcn_cvt_pk_fp8_f32)
    return (unsigned char)(__builtin_amdgcn_cvt_pk_fp8_f32(f, f, 0, false) & 0xFF);
#else
    if (!(f > 0.f)) return 0;
    if (f >= 448.f) return 0x7E;
    int e; float m = frexpf(f, &e);            // f = m*2^e, m in [0.5,1)
    if (e >= -5) {                              // normal: f >= 2^-6
        int mant = (int)roundf(m * 16.f) - 8;   // 0..8
        int ef = e + 6;
        if (mant == 8) { mant = 0; ef += 1; }
        if (ef >= 16) return 0x7E;
        return (unsigned char)((ef << 3) | mant);
    }
    int mant = (int)roundf(f * 512.f);          // subnormal
    if (mant >= 8) return 0x08;
    return (unsigned char)mant;
#endif
}

__device__ inline unsigned int pack4_e4m3(float a, float b, float c, float d) {
#if __has_builtin(__builtin_amdgcn_cvt_pk_fp8_f32)
    unsigned int w = 0;
    w = (unsigned int)__builtin_amdgcn_cvt_pk_fp8_f32(a, b, (int)w, false);
    w = (unsigned int)__builtin_amdgcn_cvt_pk_fp8_f32(c, d, (int)w, true);
    return w;
#else
    return (unsigned int)f32_to_e4m3(a) | ((unsigned int)f32_to_e4m3(b) << 8)
         | ((unsigned int)f32_to_e4m3(c) << 16) | ((unsigned int)f32_to_e4m3(d) << 24);
#endif
}

__device__ inline unsigned short f2bf_rne(float f) {
    unsigned int u = __float_as_uint(f);
    u += 0x7FFFu + ((u >> 16) & 1u);
    return (unsigned short)(u >> 16);
}

// ---------------------------------------------------------------- stats1
__global__ __launch_bounds__(256) void stats1(const float* __restrict__ X,
                                              unsigned short* __restrict__ Xbf,
                                              float* __restrict__ sq,
                                              float* __restrict__ pcol,
                                              float* __restrict__ ptot) {
    const int blk = blockIdx.x;          // 0 .. BB*32-1
    const int b   = blk & 7;
    const int ch  = blk >> 3;            // 0..31
    const int r0  = ch * 64;
    const int t = threadIdx.x, w = t >> 6, lane = t & 63;
    const float* Xb = X + (size_t)b * NN * DD;
    unsigned short* Xbfb = Xbf + (size_t)b * NN * DD;
    float cs = 0.f, sqtot = 0.f;
    #pragma unroll
    for (int i = w; i < 64; i += 4) {
        const int row = r0 + i;
        float x = Xb[(size_t)row * DD + lane];
        unsigned short hb = f2bf_rne(x);
        Xbfb[(size_t)row * DD + lane] = hb;
        float xr = __uint_as_float((unsigned int)hb << 16);
        cs += xr;
        float s = xr * xr;
        #pragma unroll
        for (int off = 32; off > 0; off >>= 1) s += __shfl_down(s, off);
        if (lane == 0) { sq[b * NN + row] = s; sqtot += s; }
    }
    __shared__ float colS[4][64];
    __shared__ float totS[4];
    colS[w][lane] = cs;
    if (lane == 0) totS[w] = sqtot;
    __syncthreads();
    if (t < 64)
        pcol[(b * 32 + ch) * 64 + t] = colS[0][t] + colS[1][t] + colS[2][t] + colS[3][t];
    if (t == 0)
        ptot[b * 32 + ch] = totS[0] + totS[1] + totS[2] + totS[3];
}

// ---------------------------------------------------------------- stats2
__global__ void stats2(const float* __restrict__ pcol,
                       const float* __restrict__ ptot,
                       float* __restrict__ scale) {
    const int b = blockIdx.x, t = threadIdx.x;   // 64 threads
    float c = 0.f;
    #pragma unroll
    for (int p = 0; p < 32; ++p) c += pcol[(b * 32 + p) * 64 + t];
    float s2 = c * c;
    #pragma unroll
    for (int off = 32; off > 0; off >>= 1) s2 += __shfl_down(s2, off);
    if (t == 0) {
        float T = 0.f;
        #pragma unroll
        for (int p = 0; p < 32; ++p) T += ptot[b * 32 + p];
        float cmean = 2.0f * T / (float)NN
                    - 2.0f * s2 / ((float)NN * (float)NN) + 1e-8f;
        scale[b] = -1.0f / (cmean * EPS);
    }
}

// ---------------------------------------------------------------- init (outW only)
__global__ void init_w(float* __restrict__ outW) {
    outW[blockIdx.x * 256 + threadIdx.x] = 1.0f / (float)NN;
}

// ---------------------------------------------------------------- build_K
// K8[b,n,m] = e4m3( KSCALE * exp(scale*(sq[n]+sq[m]-2*gram)) ), diag stored 0.
// Also emits per-tile row-sum partials (unquantized) -> rsum[b][mt][n],
// which replaces the first sink sweep (v=1).
__global__ __launch_bounds__(256) void build_K(const unsigned short* __restrict__ Xbf,
                                               const float* __restrict__ sq,
                                               const float* __restrict__ scale,
                                               unsigned char* __restrict__ K,
                                               float* __restrict__ rsum) {
    __shared__ float T[64][68];
    const int bid = blockIdx.x;                   // 0..8191
    const int b = bid & 7, tix = bid >> 3;        // tix 0..1023
    const int nt = tix & 31, mt = tix >> 5;
    const int t = threadIdx.x, w = t >> 6;
    const int lane = t & 63, l31 = lane & 31, lh = lane >> 5;
    const int wr = w >> 1, wc = w & 1;            // 32x32 quadrant of 64x64 tile
    const unsigned short* Xb = Xbf + (size_t)b * NN * DD;
    const int n_row = nt * 64 + wr * 32 + l31;    // A: lane holds row l31
    const int m_row = mt * 64 + wc * 32 + l31;    // B: lane holds col l31
    bf16x8 af[4], bf[4];
    #pragma unroll
    for (int s = 0; s < 4; ++s) {                 // k = s*16 + lh*8 + (0..7)
        af[s] = *(const bf16x8*)(Xb + (size_t)n_row * DD + s * 16 + lh * 8);
        bf[s] = *(const bf16x8*)(Xb + (size_t)m_row * DD + s * 16 + lh * 8);
    }
    f32x16 acc = {};
    #pragma unroll
    for (int s = 0; s < 4; ++s)
        acc = __builtin_amdgcn_mfma_f32_32x32x16_bf16(af[s], bf[s], acc, 0, 0, 0);
    // C/D: col = l31, row = (r&3) + 8*(r>>2) + 4*lh   [m74/m101 verified]
    const float sc = scale[b];
    const float* sqb = sq + b * NN;
    const int gm = mt * 64 + wc * 32 + l31;
    const float sqm = sqb[gm];
    #pragma unroll
    for (int r = 0; r < 16; ++r) {
        const int row = (r & 3) + 8 * (r >> 2) + 4 * lh;
        const int gn = nt * 64 + wr * 32 + row;
        float val = KSCALE * __expf(sc * (sqb[gn] + sqm - 2.0f * acc[r]));
        T[wr * 32 + row][wc * 32 + l31] = (gn == gm) ? 0.0f : val;
    }
    __syncthreads();
    // re-read row-major, pack 16 fp8/thread, one uint4 store per thread
    const int orow = t >> 2, oseg = t & 3;        // 64 rows x 4 segs of 16
    float vv[16];
    #pragma unroll
    for (int j = 0; j < 4; ++j)
        *(float4*)&vv[j * 4] = *(const float4*)&T[orow][oseg * 16 + j * 4];
    // row-sum partial (unquantized, diag excluded since T holds 0 there)
    float rs = 0.f;
    #pragma unroll
    for (int j = 0; j < 16; ++j) rs += vv[j];
    rs += __shfl_down(rs, 2);
    rs += __shfl_down(rs, 1);
    if (oseg == 0)
        rsum[((size_t)b * 32 + mt) * NN + nt * 64 + orow] = rs;
    uint4 o;
    o.x = pack4_e4m3(vv[0],  vv[1],  vv[2],  vv[3]);
    o.y = pack4_e4m3(vv[4],  vv[5],  vv[6],  vv[7]);
    o.z = pack4_e4m3(vv[8],  vv[9],  vv[10], vv[11]);
    o.w = pack4_e4m3(vv[12], vv[13], vv[14], vv[15]);
    unsigned char* Kb = K + (size_t)b * NN * NN;
    *(uint4*)(Kb + (size_t)(nt * 64 + orow) * NN + mt * 64 + oseg * 16) = o;
}

// ---------------------------------------------------------------- ucombine
// u1[b,n] = (w+1e-16) / ( sum_mt rsum[b][mt][n] + KSCALE )   (v=1 pass, free)
__global__ __launch_bounds__(256) void ucombine(const float* __restrict__ rsum,
                                                const float* __restrict__ W,
                                                float* __restrict__ u) {
    const int idx = blockIdx.x * 256 + threadIdx.x;   // 0..16383
    const int b = idx >> 11, n = idx & (NN - 1);
    float s = 0.f;
    #pragma unroll
    for (int mt = 0; mt < 32; ++mt)
        s += rsum[((size_t)b * 32 + mt) * NN + n];
    u[idx] = (W[idx] + 1e-16f) / (s + KSCALE);
}

// ---------------------------------------------------------------- sink_pass
// MODE 0: u[n] = (w[n]+1e-16) / ( sum_m K8[n,m]*v[m] + KSCALE*v[n] )
// MODE 1: v[m] = (1/N)        / ( sum_n K8[m,n]*u[n] + KSCALE*u[m] )
// 8 rows/block (2/wave interleaved), uint4 K loads (16 fp8/lane/instr).
template <int MODE>
__global__ __launch_bounds__(256) void sink_pass(const unsigned char* __restrict__ K,
                                                 const float* __restrict__ vin,
                                                 const float* __restrict__ wts,
                                                 float* __restrict__ out) {
    __shared__ float vs[NN];
    const int bid = blockIdx.x;                   // 0..2047
    const int b = bid & 7, j = bid >> 3;          // j 0..255
    const int t = threadIdx.x, w = t >> 6, lane = t & 63;
    const float* vb = vin + (size_t)b * NN;
    #pragma unroll
    for (int s = 0; s < 2; ++s)
        *(float4*)&vs[(t + s * 256) * 4] = *(const float4*)&vb[(t + s * 256) * 4];
    __syncthreads();
    const int r0 = j * 8 + w * 2;                 // 2 rows per wave
    const unsigned char* Kr0 = K + ((size_t)b * NN + r0) * NN;
    const unsigned char* Kr1 = Kr0 + NN;
    float a0 = 0.f, a1 = 0.f;
    #pragma unroll
    for (int it = 0; it < 2; ++it) {
        const int m0 = it * 1024 + lane * 16;
        const uint4 ka = *(const uint4*)(Kr0 + m0);
        const uint4 kb = *(const uint4*)(Kr1 + m0);
        const float4 v0 = *(const float4*)&vs[m0];
        const float4 v1 = *(const float4*)&vs[m0 + 4];
        const float4 v2 = *(const float4*)&vs[m0 + 8];
        const float4 v3 = *(const float4*)&vs[m0 + 12];
        {
            f32x2 q0 = cvt2_fp8<false>(ka.x), q1 = cvt2_fp8<true>(ka.x);
            f32x2 q2 = cvt2_fp8<false>(ka.y), q3 = cvt2_fp8<true>(ka.y);
            f32x2 q4 = cvt2_fp8<false>(ka.z), q5 = cvt2_fp8<true>(ka.z);
            f32x2 q6 = cvt2_fp8<false>(ka.w), q7 = cvt2_fp8<true>(ka.w);
            a0 += q0[0]*v0.x + q0[1]*v0.y + q1[0]*v0.z + q1[1]*v0.w
                + q2[0]*v1.x + q2[1]*v1.y + q3[0]*v1.z + q3[1]*v1.w
                + q4[0]*v2.x + q4[1]*v2.y + q5[0]*v2.z + q5[1]*v2.w
                + q6[0]*v3.x + q6[1]*v3.y + q7[0]*v3.z + q7[1]*v3.w;
        }
        {
            f32x2 q0 = cvt2_fp8<false>(kb.x), q1 = cvt2_fp8<true>(kb.x);
            f32x2 q2 = cvt2_fp8<false>(kb.y), q3 = cvt2_fp8<true>(kb.y);
            f32x2 q4 = cvt2_fp8<false>(kb.z), q5 = cvt2_fp8<true>(kb.z);
            f32x2 q6 = cvt2_fp8<false>(kb.w), q7 = cvt2_fp8<true>(kb.w);
            a1 += q0[0]*v0.x + q0[1]*v0.y + q1[0]*v0.z + q1[1]*v0.w
                + q2[0]*v1.x + q2[1]*v1.y + q3[0]*v1.z + q3[1]*v1.w
                + q4[0]*v2.x + q4[1]*v2.y + q5[0]*v2.z + q5[1]*v2.w
                + q6[0]*v3.x + q6[1]*v3.y + q7[0]*v3.z + q7[1]*v3.w;
        }
    }
    #pragma unroll
    for (int off = 32; off > 0; off >>= 1) {
        a0 += __shfl_down(a0, off);
        a1 += __shfl_down(a1, off);
    }
    if (lane == 0) {
        const float n0 = (MODE == 0) ? (wts[(size_t)b*NN + r0] + 1e-16f) : (1.0f/(float)NN);
        const float n1 = (MODE == 0) ? (wts[(size_t)b*NN + r0 + 1] + 1e-16f) : (1.0f/(float)NN);
        out[(size_t)b * NN + r0]     = n0 / (a0 + KSCALE * vs[r0]);
        out[(size_t)b * NN + r0 + 1] = n1 / (a1 + KSCALE * vs[r0 + 1]);
    }
}

// ---------------------------------------------------------------- yprep
// Yt[b][d][n] = bf16( u[b][n] * X[b][n][d] )   (transposed for MFMA B-frags)
__global__ __launch_bounds__(256) void yprep(const float* __restrict__ X,
                                             const float* __restrict__ u,
                                             unsigned short* __restrict__ Yt) {
    __shared__ float T[64][65];
    const int bid = blockIdx.x;                   // 0..255
    const int b = bid & 7, nt = bid >> 3;
    const int t = threadIdx.x;
    const int nl = t >> 2, c0 = (t & 3) << 4;
    const float* Xb = X + ((size_t)b * NN + nt * 64) * DD;
    const float uu = u[(size_t)b * NN + nt * 64 + nl];
    #pragma unroll
    for (int j = 0; j < 4; ++j) {
        float4 x = *(const float4*)(Xb + (size_t)nl * DD + c0 + j * 4);
        T[c0 + j * 4 + 0][nl] = uu * x.x;
        T[c0 + j * 4 + 1][nl] = uu * x.y;
        T[c0 + j * 4 + 2][nl] = uu * x.z;
        T[c0 + j * 4 + 3][nl] = uu * x.w;
    }
    __syncthreads();
    const int d = t >> 2, n0 = (t & 3) << 4;
    unsigned short* Yr = Yt + ((size_t)b * DD + d) * NN + nt * 64 + n0;
    unsigned int ow[8];
    #pragma unroll
    for (int j = 0; j < 8; ++j) {
        unsigned int lo = f2bf_rne(T[d][n0 + 2 * j]);
        unsigned int hi = f2bf_rne(T[d][n0 + 2 * j + 1]);
        ow[j] = lo | (hi << 16);
    }
    *(uint4*)(Yr)     = make_uint4(ow[0], ow[1], ow[2], ow[3]);
    *(uint4*)(Yr + 8) = make_uint4(ow[4], ow[5], ow[6], ow[7]);
}

// ---------------------------------------------------------------- out_gemm
// pbuf[nc,b,m,d] = sum_{n in chunk} K8[m,n]*u[n]*x[n,d]  via bf16 MFMA.
// Also (wc==0 waves) dpart[nc][b][m] = sum_{n in chunk} K8[m,n]*u[n]
// -> fuses the final v-update sweep into this kernel.
__global__ __launch_bounds__(256) void out_gemm(const unsigned char* __restrict__ K,
                                                const unsigned short* __restrict__ Yt,
                                                const float* __restrict__ u,
                                                float* __restrict__ pbuf,
                                                float* __restrict__ dpart) {
    const int bid = blockIdx.x;                   // 0..1023
    const int b = bid & 7, tix = bid >> 3;        // tix 0..127
    const int nc = tix & (NC - 1), mt = tix >> 2; // mt 0..31
    const int t = threadIdx.x, w = t >> 6, lane = t & 63;
    const int l31 = lane & 31, lh = lane >> 5;
    const int wr = w >> 1, wc = w & 1;
    const unsigned char*  Kr = K  + ((size_t)b * NN + mt * 64 + wr * 32 + l31) * NN;
    const unsigned short* Yr = Yt + ((size_t)b * DD + wc * 32 + l31) * NN;
    const float* ub = u + (size_t)b * NN;
    f32x16 acc = {};
    float ds = 0.f;
    #pragma unroll 4
    for (int st = 0; st < (NN / NC) / 16; ++st) {
        const int n = nc * (NN / NC) + st * 16 + lh * 8;
        const uint2 k8 = *(const uint2*)(Kr + n);
        f32x2 p0 = cvt2_fp8<false>(k8.x);
        f32x2 p1 = cvt2_fp8<true>(k8.x);
        f32x2 p2 = cvt2_fp8<false>(k8.y);
        f32x2 p3 = cvt2_fp8<true>(k8.y);
        if (wc == 0) {
            const float4 ua = *(const float4*)(ub + n);
            const float4 uc = *(const float4*)(ub + n + 4);
            ds += p0[0]*ua.x + p0[1]*ua.y + p1[0]*ua.z + p1[1]*ua.w
                + p2[0]*uc.x + p2[1]*uc.y + p3[0]*uc.z + p3[1]*uc.w;
        }
        union { unsigned int u4[4]; bf16x8 v8; } av;
        av.u4[0] = __builtin_amdgcn_perm(__float_as_uint(p0[1]), __float_as_uint(p0[0]), 0x07060302);
        av.u4[1] = __builtin_amdgcn_perm(__float_as_uint(p1[1]), __float_as_uint(p1[0]), 0x07060302);
        av.u4[2] = __builtin_amdgcn_perm(__float_as_uint(p2[1]), __float_as_uint(p2[0]), 0x07060302);
        av.u4[3] = __builtin_amdgcn_perm(__float_as_uint(p3[1]), __float_as_uint(p3[0]), 0x07060302);
        bf16x8 bv = *(const bf16x8*)(Yr + n);
        acc = __builtin_amdgcn_mfma_f32_32x32x16_bf16(av.v8, bv, acc, 0, 0, 0);
    }
    ds += __shfl_down(ds, 32);
    if (wc == 0 && lh == 0)
        dpart[((size_t)nc * BB + b) * NN + mt * 64 + wr * 32 + l31] = ds;
    float* pb = pbuf + (((size_t)nc * BB + b) * NN + mt * 64 + wr * 32) * DD
              + wc * 32 + l31;
    #pragma unroll
    for (int r = 0; r < 16; ++r) {
        const int row = (r & 3) + 8 * (r >> 2) + 4 * lh;
        pb[(size_t)row * DD] = acc[r];
    }
}

// ---------------------------------------------------------------- out_reduce
// denom[m] = sum_nc dpart + KSCALE*u[m]  (-> v10 = (1/N)/denom)
// out[b,m,d] = ( sum_nc pbuf + KSCALE*u[m]*x[m,d] ) / denom[m]
__global__ __launch_bounds__(256) void out_reduce(const float* __restrict__ pbuf,
                                                  const float* __restrict__ dpart,
                                                  const float* __restrict__ u,
                                                  const float* __restrict__ X,
                                                  float* __restrict__ outP) {
    const int idx = blockIdx.x * 256 + threadIdx.x;   // per float4
    const int d4 = idx & (DD / 4 - 1);
    const int bm = idx >> 4;                           // b*NN + m
    float4 s = make_float4(0.f, 0.f, 0.f, 0.f);
    float denom = 0.f;
    #pragma unroll
    for (int nc = 0; nc < NC; ++nc) {
        float4 p = *(const float4*)(pbuf + (size_t)nc * BB * NN * DD
                                    + (size_t)bm * DD + d4 * 4);
        s.x += p.x; s.y += p.y; s.z += p.z; s.w += p.w;
        denom += dpart[(size_t)nc * BB * NN + bm];
    }
    const float um = KSCALE * u[bm];
    denom += um;
    float4 xx = *(const float4*)(X + (size_t)bm * DD + d4 * 4);
    s.x += um * xx.x; s.y += um * xx.y; s.z += um * xx.z; s.w += um * xx.w;
    const float inv = 1.0f / denom;
    *(float4*)(outP + (size_t)bm * DD + d4 * 4) =
        make_float4(inv * s.x, inv * s.y, inv * s.z, inv * s.w);
}

// ---------------------------------------------------------------- launch
extern "C" void kernel_launch(void* const* d_in, const int* in_sizes, int n_in,
                              void* d_out, int out_size, void* d_ws, size_t ws_size,
                              hipStream_t stream) {
    const float* X = (const float*)d_in[0];   // particles [B,N,D]
    const float* W = (const float*)d_in[1];   // weights   [B,N]
    float* outP = (float*)d_out;                       // [B,N,D]
    float* outW = outP + (size_t)BB * NN * DD;         // [B,N]

    float* ws = (float*)d_ws;
    const size_t nfloats = (size_t)BB * NN          // sq
                         + 16                       // scale
                         + 2 * (size_t)BB * NN      // u, v
                         + (size_t)BB * 32 * 64 + BB * 32   // pcol, ptot
                         + (size_t)NC * BB * NN * DD        // pbuf
                         + (size_t)BB * 32 * NN             // rsum
                         + (size_t)NC * BB * NN;            // dpart
    const size_t need = nfloats * 4
                      + (size_t)BB * NN * DD * 2    // Xbf
                      + (size_t)BB * DD * NN * 2    // Yt
                      + (size_t)BB * NN * NN;       // K fp8
    if (ws_size < need) return;

    float* sq    = ws;
    float* scale = sq + (size_t)BB * NN;
    float* u     = scale + 16;
    float* v     = u + (size_t)BB * NN;
    float* pcol  = v + (size_t)BB * NN;
    float* ptot  = pcol + (size_t)BB * 32 * 64;
    float* pbuf  = ptot + BB * 32;
    float* rsum  = pbuf + (size_t)NC * BB * NN * DD;
    float* dpart = rsum + (size_t)BB * 32 * NN;
    unsigned short* Xbf = (unsigned short*)(dpart + (size_t)NC * BB * NN);
    unsigned short* Yt  = Xbf + (size_t)BB * NN * DD;
    unsigned char*  K   = (unsigned char*)(Yt + (size_t)BB * DD * NN);

    stats1<<<dim3(BB * 32), 256, 0, stream>>>(X, Xbf, sq, pcol, ptot);
    stats2<<<dim3(BB), 64, 0, stream>>>(pcol, ptot, scale);
    init_w<<<dim3(BB * NN / 256), 256, 0, stream>>>(outW);
    build_K<<<dim3(32 * 32 * BB), 256, 0, stream>>>(Xbf, sq, scale, K, rsum);
    ucombine<<<dim3(BB * NN / 256), 256, 0, stream>>>(rsum, W, u);   // u1 (v=1)
    for (int i = 0; i < ITERS - 1; ++i) {
        sink_pass<1><<<dim3(BB * NN / 8), 256, 0, stream>>>(K, u, W, v);  // v_i
        sink_pass<0><<<dim3(BB * NN / 8), 256, 0, stream>>>(K, v, W, u);  // u_{i+1}
    }
    yprep<<<dim3(BB * NN / 64), 256, 0, stream>>>(X, u, Yt);
    out_gemm<<<dim3((NN / 64) * NC * BB), 256, 0, stream>>>(K, Yt, u, pbuf, dpart);
    out_reduce<<<dim3(BB * NN * DD / 4 / 256), 256, 0, stream>>>(pbuf, dpart, u, X, outP);
}

// Round 9
// 185.024 us; speedup vs baseline: 3.5736x; 1.0891x over previous
//
#include <hip/hip_runtime.h>

#define BB 8
#define NN 2048
#define DD 64
#define NC 4            // split-K chunks for out_gemm
constexpr float EPS = 0.1f;
constexpr int ITERS = 10;
constexpr float KSCALE = 4096.0f;   // off-diag fp8 scale; diag handled analytically

typedef short bf16x8 __attribute__((ext_vector_type(8)));
typedef float f32x16 __attribute__((ext_vector_type(16)));
typedef float f32x2  __attribute__((ext_vector_type(2)));

// ---------------------------------------------------------------- fp8 helpers
__device__ inline float e4m3_to_f32_manual(unsigned int b) {
    unsigned int e = (b >> 3) & 15u, m = b & 7u;
    float v;
    if (e == 0) v = (float)m * 0.001953125f;              // m * 2^-9
    else        v = __uint_as_float(((e + 120u) << 23) | (m << 20));
    return (b & 0x80u) ? -v : v;
}

template <bool HI>
__device__ inline f32x2 cvt2_fp8(unsigned int w) {
#if __has_builtin(__builtin_amdgcn_cvt_pk_f32_fp8)
    return __builtin_amdgcn_cvt_pk_f32_fp8(w, HI);
#else
    f32x2 r; unsigned int s = HI ? (w >> 16) : w;
    r[0] = e4m3_to_f32_manual(s & 255u);
    r[1] = e4m3_to_f32_manual((s >> 8) & 255u);
    return r;
#endif
}

__device__ inline unsigned char f32_to_e4m3(float f) {   // f in [0, 448]
#if __has_builtin(__builtin_amdgcn_cvt_pk_fp8_f32)
    return (unsigned char)(__builtin_amdgcn_cvt_pk_fp8_f32(f, f, 0, false) & 0xFF);
#else
    if (!(f > 0.f)) return 0;
    if (f >= 448.f) return 0x7E;
    int e; float m = frexpf(f, &e);            // f = m*2^e, m in [0.5,1)
    if (e >= -5) {                              // normal: f >= 2^-6
        int mant = (int)roundf(m * 16.f) - 8;   // 0..8
        int ef = e + 6;
        if (mant == 8) { mant = 0; ef += 1; }
        if (ef >= 16) return 0x7E;
        return (unsigned char)((ef << 3) | mant);
    }
    int mant = (int)roundf(f * 512.f);          // subnormal
    if (mant >= 8) return 0x08;
    return (unsigned char)mant;
#endif
}

__device__ inline unsigned int pack4_e4m3(float a, float b, float c, float d) {
#if __has_builtin(__builtin_amdgcn_cvt_pk_fp8_f32)
    unsigned int w = 0;
    w = (unsigned int)__builtin_amdgcn_cvt_pk_fp8_f32(a, b, (int)w, false);
    w = (unsigned int)__builtin_amdgcn_cvt_pk_fp8_f32(c, d, (int)w, true);
    return w;
#else
    return (unsigned int)f32_to_e4m3(a) | ((unsigned int)f32_to_e4m3(b) << 8)
         | ((unsigned int)f32_to_e4m3(c) << 16) | ((unsigned int)f32_to_e4m3(d) << 24);
#endif
}

__device__ inline unsigned short f2bf_rne(float f) {
    unsigned int u = __float_as_uint(f);
    u += 0x7FFFu + ((u >> 16) & 1u);
    return (unsigned short)(u >> 16);
}

// ---------------------------------------------------------------- stats1
// Also initializes outW (folded former init_w launch).
__global__ __launch_bounds__(256) void stats1(const float* __restrict__ X,
                                              unsigned short* __restrict__ Xbf,
                                              float* __restrict__ sq,
                                              float* __restrict__ pcol,
                                              float* __restrict__ ptot,
                                              float* __restrict__ outW) {
    const int blk = blockIdx.x;          // 0 .. BB*32-1
    const int b   = blk & 7;
    const int ch  = blk >> 3;            // 0..31
    const int r0  = ch * 64;
    const int t = threadIdx.x, w = t >> 6, lane = t & 63;
    const int gidx = blk * 256 + t;
    if (gidx < BB * NN) outW[gidx] = 1.0f / (float)NN;
    const float* Xb = X + (size_t)b * NN * DD;
    unsigned short* Xbfb = Xbf + (size_t)b * NN * DD;
    float cs = 0.f, sqtot = 0.f;
    #pragma unroll
    for (int i = w; i < 64; i += 4) {
        const int row = r0 + i;
        float x = Xb[(size_t)row * DD + lane];
        unsigned short hb = f2bf_rne(x);
        Xbfb[(size_t)row * DD + lane] = hb;
        float xr = __uint_as_float((unsigned int)hb << 16);
        cs += xr;
        float s = xr * xr;
        #pragma unroll
        for (int off = 32; off > 0; off >>= 1) s += __shfl_down(s, off);
        if (lane == 0) { sq[b * NN + row] = s; sqtot += s; }
    }
    __shared__ float colS[4][64];
    __shared__ float totS[4];
    colS[w][lane] = cs;
    if (lane == 0) totS[w] = sqtot;
    __syncthreads();
    if (t < 64)
        pcol[(b * 32 + ch) * 64 + t] = colS[0][t] + colS[1][t] + colS[2][t] + colS[3][t];
    if (t == 0)
        ptot[b * 32 + ch] = totS[0] + totS[1] + totS[2] + totS[3];
}

// ---------------------------------------------------------------- stats2
__global__ void stats2(const float* __restrict__ pcol,
                       const float* __restrict__ ptot,
                       float* __restrict__ scale) {
    const int b = blockIdx.x, t = threadIdx.x;   // 64 threads
    float c = 0.f;
    #pragma unroll
    for (int p = 0; p < 32; ++p) c += pcol[(b * 32 + p) * 64 + t];
    float s2 = c * c;
    #pragma unroll
    for (int off = 32; off > 0; off >>= 1) s2 += __shfl_down(s2, off);
    if (t == 0) {
        float T = 0.f;
        #pragma unroll
        for (int p = 0; p < 32; ++p) T += ptot[b * 32 + p];
        float cmean = 2.0f * T / (float)NN
                    - 2.0f * s2 / ((float)NN * (float)NN) + 1e-8f;
        scale[b] = -1.0f / (cmean * EPS);
    }
}

// ---------------------------------------------------------------- build_K
// SYMMETRIC: one block per unordered tile pair (I<=J) per batch (528*8 blocks).
// Computes the 64x64 gram once, writes K[I-rows][J-cols] AND its transpose
// K[J-rows][I-cols] from the LDS tile. Emits rsum row-sums (slot [b][J][n in I])
// and col-sums (slot [b][I][n in J]) for the free u1 (v=1) pass.
__global__ __launch_bounds__(256) void build_K(const unsigned short* __restrict__ Xbf,
                                               const float* __restrict__ sq,
                                               const float* __restrict__ scale,
                                               unsigned char* __restrict__ K,
                                               float* __restrict__ rsum) {
    __shared__ float T[64][68];
    const int bid = blockIdx.x;                   // 0..4223
    const int b = bid & 7;
    int q = bid >> 3, I = 0;                      // triangular decode (uniform)
    while (q >= 32 - I) { q -= 32 - I; ++I; }
    const int J = I + q;                          // I <= J
    const int t = threadIdx.x, w = t >> 6;
    const int lane = t & 63, l31 = lane & 31, lh = lane >> 5;
    const int wr = w >> 1, wc = w & 1;            // 32x32 quadrant of 64x64 tile
    const unsigned short* Xb = Xbf + (size_t)b * NN * DD;
    const int n_row = I * 64 + wr * 32 + l31;     // A: lane holds row l31 (I side)
    const int m_row = J * 64 + wc * 32 + l31;     // B: lane holds col l31 (J side)
    bf16x8 af[4], bf[4];
    #pragma unroll
    for (int s = 0; s < 4; ++s) {                 // k = s*16 + lh*8 + (0..7)
        af[s] = *(const bf16x8*)(Xb + (size_t)n_row * DD + s * 16 + lh * 8);
        bf[s] = *(const bf16x8*)(Xb + (size_t)m_row * DD + s * 16 + lh * 8);
    }
    f32x16 acc = {};
    #pragma unroll
    for (int s = 0; s < 4; ++s)
        acc = __builtin_amdgcn_mfma_f32_32x32x16_bf16(af[s], bf[s], acc, 0, 0, 0);
    // C/D: col = l31, row = (r&3) + 8*(r>>2) + 4*lh   [m74/m101 verified]
    const float sc = scale[b];
    const float* sqb = sq + b * NN;
    const int gm = J * 64 + wc * 32 + l31;
    const float sqm = sqb[gm];
    #pragma unroll
    for (int r = 0; r < 16; ++r) {
        const int row = (r & 3) + 8 * (r >> 2) + 4 * lh;
        const int gn = I * 64 + wr * 32 + row;
        float val = KSCALE * __expf(sc * (sqb[gn] + sqm - 2.0f * acc[r]));
        T[wr * 32 + row][wc * 32 + l31] = (gn == gm) ? 0.0f : val;
    }
    __syncthreads();
    unsigned char* Kb = K + (size_t)b * NN * NN;
    // ---- store 1: K[I-rows][J-cols], row-major from LDS, + row-sums
    {
        const int orow = t >> 2, oseg = t & 3;    // 64 rows x 4 segs of 16
        float vv[16];
        #pragma unroll
        for (int j = 0; j < 4; ++j)
            *(float4*)&vv[j * 4] = *(const float4*)&T[orow][oseg * 16 + j * 4];
        float rs = 0.f;
        #pragma unroll
        for (int j = 0; j < 16; ++j) rs += vv[j];
        rs += __shfl_down(rs, 2);
        rs += __shfl_down(rs, 1);
        if (oseg == 0)
            rsum[((size_t)b * 32 + J) * NN + I * 64 + orow] = rs;
        uint4 o;
        o.x = pack4_e4m3(vv[0],  vv[1],  vv[2],  vv[3]);
        o.y = pack4_e4m3(vv[4],  vv[5],  vv[6],  vv[7]);
        o.z = pack4_e4m3(vv[8],  vv[9],  vv[10], vv[11]);
        o.w = pack4_e4m3(vv[12], vv[13], vv[14], vv[15]);
        *(uint4*)(Kb + (size_t)(I * 64 + orow) * NN + J * 64 + oseg * 16) = o;
    }
    // ---- store 2 (I<J only): transpose tile -> K[J-rows][I-cols], + col-sums
    if (I != J) {
        const int c = t >> 2, rseg = t & 3;       // 64 cols x 4 segs of 16 rows
        float vv[16];
        #pragma unroll
        for (int j = 0; j < 16; ++j) vv[j] = T[rseg * 16 + j][c];
        float csum = 0.f;
        #pragma unroll
        for (int j = 0; j < 16; ++j) csum += vv[j];
        csum += __shfl_down(csum, 2);
        csum += __shfl_down(csum, 1);
        if (rseg == 0)
            rsum[((size_t)b * 32 + I) * NN + J * 64 + c] = csum;
        uint4 o;
        o.x = pack4_e4m3(vv[0],  vv[1],  vv[2],  vv[3]);
        o.y = pack4_e4m3(vv[4],  vv[5],  vv[6],  vv[7]);
        o.z = pack4_e4m3(vv[8],  vv[9],  vv[10], vv[11]);
        o.w = pack4_e4m3(vv[12], vv[13], vv[14], vv[15]);
        *(uint4*)(Kb + (size_t)(J * 64 + c) * NN + I * 64 + rseg * 16) = o;
    }
}

// ---------------------------------------------------------------- ucombine
// u1[b,n] = (w+1e-16) / ( sum_g rsum[b][g][n] + KSCALE )   (v=1 pass, free)
__global__ __launch_bounds__(256) void ucombine(const float* __restrict__ rsum,
                                                const float* __restrict__ W,
                                                float* __restrict__ u) {
    const int idx = blockIdx.x * 256 + threadIdx.x;   // 0..16383
    const int b = idx >> 11, n = idx & (NN - 1);
    float s = 0.f;
    #pragma unroll
    for (int g = 0; g < 32; ++g)
        s += rsum[((size_t)b * 32 + g) * NN + n];
    u[idx] = (W[idx] + 1e-16f) / (s + KSCALE);
}

// ---------------------------------------------------------------- sink_pass
// MODE 0: u[n] = (w[n]+1e-16) / ( sum_m K8[n,m]*v[m] + KSCALE*v[n] )
// MODE 1: v[m] = (1/N)        / ( sum_n K8[m,n]*u[n] + KSCALE*u[m] )
// 8 rows/block (2/wave interleaved), uint4 K loads (16 fp8/lane/instr).
template <int MODE>
__global__ __launch_bounds__(256) void sink_pass(const unsigned char* __restrict__ K,
                                                 const float* __restrict__ vin,
                                                 const float* __restrict__ wts,
                                                 float* __restrict__ out) {
    __shared__ float vs[NN];
    const int bid = blockIdx.x;                   // 0..2047
    const int b = bid & 7, j = bid >> 3;          // j 0..255
    const int t = threadIdx.x, w = t >> 6, lane = t & 63;
    const float* vb = vin + (size_t)b * NN;
    #pragma unroll
    for (int s = 0; s < 2; ++s)
        *(float4*)&vs[(t + s * 256) * 4] = *(const float4*)&vb[(t + s * 256) * 4];
    __syncthreads();
    const int r0 = j * 8 + w * 2;                 // 2 rows per wave
    const unsigned char* Kr0 = K + ((size_t)b * NN + r0) * NN;
    const unsigned char* Kr1 = Kr0 + NN;
    float a0 = 0.f, a1 = 0.f;
    #pragma unroll
    for (int it = 0; it < 2; ++it) {
        const int m0 = it * 1024 + lane * 16;
        const uint4 ka = *(const uint4*)(Kr0 + m0);
        const uint4 kb = *(const uint4*)(Kr1 + m0);
        const float4 v0 = *(const float4*)&vs[m0];
        const float4 v1 = *(const float4*)&vs[m0 + 4];
        const float4 v2 = *(const float4*)&vs[m0 + 8];
        const float4 v3 = *(const float4*)&vs[m0 + 12];
        {
            f32x2 q0 = cvt2_fp8<false>(ka.x), q1 = cvt2_fp8<true>(ka.x);
            f32x2 q2 = cvt2_fp8<false>(ka.y), q3 = cvt2_fp8<true>(ka.y);
            f32x2 q4 = cvt2_fp8<false>(ka.z), q5 = cvt2_fp8<true>(ka.z);
            f32x2 q6 = cvt2_fp8<false>(ka.w), q7 = cvt2_fp8<true>(ka.w);
            a0 += q0[0]*v0.x + q0[1]*v0.y + q1[0]*v0.z + q1[1]*v0.w
                + q2[0]*v1.x + q2[1]*v1.y + q3[0]*v1.z + q3[1]*v1.w
                + q4[0]*v2.x + q4[1]*v2.y + q5[0]*v2.z + q5[1]*v2.w
                + q6[0]*v3.x + q6[1]*v3.y + q7[0]*v3.z + q7[1]*v3.w;
        }
        {
            f32x2 q0 = cvt2_fp8<false>(kb.x), q1 = cvt2_fp8<true>(kb.x);
            f32x2 q2 = cvt2_fp8<false>(kb.y), q3 = cvt2_fp8<true>(kb.y);
            f32x2 q4 = cvt2_fp8<false>(kb.z), q5 = cvt2_fp8<true>(kb.z);
            f32x2 q6 = cvt2_fp8<false>(kb.w), q7 = cvt2_fp8<true>(kb.w);
            a1 += q0[0]*v0.x + q0[1]*v0.y + q1[0]*v0.z + q1[1]*v0.w
                + q2[0]*v1.x + q2[1]*v1.y + q3[0]*v1.z + q3[1]*v1.w
                + q4[0]*v2.x + q4[1]*v2.y + q5[0]*v2.z + q5[1]*v2.w
                + q6[0]*v3.x + q6[1]*v3.y + q7[0]*v3.z + q7[1]*v3.w;
        }
    }
    #pragma unroll
    for (int off = 32; off > 0; off >>= 1) {
        a0 += __shfl_down(a0, off);
        a1 += __shfl_down(a1, off);
    }
    if (lane == 0) {
        const float n0 = (MODE == 0) ? (wts[(size_t)b*NN + r0] + 1e-16f) : (1.0f/(float)NN);
        const float n1 = (MODE == 0) ? (wts[(size_t)b*NN + r0 + 1] + 1e-16f) : (1.0f/(float)NN);
        out[(size_t)b * NN + r0]     = n0 / (a0 + KSCALE * vs[r0]);
        out[(size_t)b * NN + r0 + 1] = n1 / (a1 + KSCALE * vs[r0 + 1]);
    }
}

// ---------------------------------------------------------------- yprep
// Yt[b][d][n] = bf16( u[b][n] * X[b][n][d] )   (transposed for MFMA B-frags)
__global__ __launch_bounds__(256) void yprep(const float* __restrict__ X,
                                             const float* __restrict__ u,
                                             unsigned short* __restrict__ Yt) {
    __shared__ float T[64][65];
    const int bid = blockIdx.x;                   // 0..255
    const int b = bid & 7, nt = bid >> 3;
    const int t = threadIdx.x;
    const int nl = t >> 2, c0 = (t & 3) << 4;
    const float* Xb = X + ((size_t)b * NN + nt * 64) * DD;
    const float uu = u[(size_t)b * NN + nt * 64 + nl];
    #pragma unroll
    for (int j = 0; j < 4; ++j) {
        float4 x = *(const float4*)(Xb + (size_t)nl * DD + c0 + j * 4);
        T[c0 + j * 4 + 0][nl] = uu * x.x;
        T[c0 + j * 4 + 1][nl] = uu * x.y;
        T[c0 + j * 4 + 2][nl] = uu * x.z;
        T[c0 + j * 4 + 3][nl] = uu * x.w;
    }
    __syncthreads();
    const int d = t >> 2, n0 = (t & 3) << 4;
    unsigned short* Yr = Yt + ((size_t)b * DD + d) * NN + nt * 64 + n0;
    unsigned int ow[8];
    #pragma unroll
    for (int j = 0; j < 8; ++j) {
        unsigned int lo = f2bf_rne(T[d][n0 + 2 * j]);
        unsigned int hi = f2bf_rne(T[d][n0 + 2 * j + 1]);
        ow[j] = lo | (hi << 16);
    }
    *(uint4*)(Yr)     = make_uint4(ow[0], ow[1], ow[2], ow[3]);
    *(uint4*)(Yr + 8) = make_uint4(ow[4], ow[5], ow[6], ow[7]);
}

// ---------------------------------------------------------------- out_gemm
// pbuf[nc,b,m,d] = sum_{n in chunk} K8[m,n]*u[n]*x[n,d]  via bf16 MFMA.
// Also (wc==0 waves) dpart[nc][b][m] = sum_{n in chunk} K8[m,n]*u[n]
// -> fuses the final v-update sweep into this kernel.
__global__ __launch_bounds__(256) void out_gemm(const unsigned char* __restrict__ K,
                                                const unsigned short* __restrict__ Yt,
                                                const float* __restrict__ u,
                                                float* __restrict__ pbuf,
                                                float* __restrict__ dpart) {
    const int bid = blockIdx.x;                   // 0..1023
    const int b = bid & 7, tix = bid >> 3;        // tix 0..127
    const int nc = tix & (NC - 1), mt = tix >> 2; // mt 0..31
    const int t = threadIdx.x, w = t >> 6, lane = t & 63;
    const int l31 = lane & 31, lh = lane >> 5;
    const int wr = w >> 1, wc = w & 1;
    const unsigned char*  Kr = K  + ((size_t)b * NN + mt * 64 + wr * 32 + l31) * NN;
    const unsigned short* Yr = Yt + ((size_t)b * DD + wc * 32 + l31) * NN;
    const float* ub = u + (size_t)b * NN;
    f32x16 acc = {};
    float ds = 0.f;
    #pragma unroll 4
    for (int st = 0; st < (NN / NC) / 16; ++st) {
        const int n = nc * (NN / NC) + st * 16 + lh * 8;
        const uint2 k8 = *(const uint2*)(Kr + n);
        f32x2 p0 = cvt2_fp8<false>(k8.x);
        f32x2 p1 = cvt2_fp8<true>(k8.x);
        f32x2 p2 = cvt2_fp8<false>(k8.y);
        f32x2 p3 = cvt2_fp8<true>(k8.y);
        if (wc == 0) {
            const float4 ua = *(const float4*)(ub + n);
            const float4 uc = *(const float4*)(ub + n + 4);
            ds += p0[0]*ua.x + p0[1]*ua.y + p1[0]*ua.z + p1[1]*ua.w
                + p2[0]*uc.x + p2[1]*uc.y + p3[0]*uc.z + p3[1]*uc.w;
        }
        union { unsigned int u4[4]; bf16x8 v8; } av;
        av.u4[0] = __builtin_amdgcn_perm(__float_as_uint(p0[1]), __float_as_uint(p0[0]), 0x07060302);
        av.u4[1] = __builtin_amdgcn_perm(__float_as_uint(p1[1]), __float_as_uint(p1[0]), 0x07060302);
        av.u4[2] = __builtin_amdgcn_perm(__float_as_uint(p2[1]), __float_as_uint(p2[0]), 0x07060302);
        av.u4[3] = __builtin_amdgcn_perm(__float_as_uint(p3[1]), __float_as_uint(p3[0]), 0x07060302);
        bf16x8 bv = *(const bf16x8*)(Yr + n);
        acc = __builtin_amdgcn_mfma_f32_32x32x16_bf16(av.v8, bv, acc, 0, 0, 0);
    }
    ds += __shfl_down(ds, 32);
    if (wc == 0 && lh == 0)
        dpart[((size_t)nc * BB + b) * NN + mt * 64 + wr * 32 + l31] = ds;
    float* pb = pbuf + (((size_t)nc * BB + b) * NN + mt * 64 + wr * 32) * DD
              + wc * 32 + l31;
    #pragma unroll
    for (int r = 0; r < 16; ++r) {
        const int row = (r & 3) + 8 * (r >> 2) + 4 * lh;
        pb[(size_t)row * DD] = acc[r];
    }
}

// ---------------------------------------------------------------- out_reduce
// denom[m] = sum_nc dpart + KSCALE*u[m]  (-> v10 = (1/N)/denom)
// out[b,m,d] = ( sum_nc pbuf + KSCALE*u[m]*x[m,d] ) / denom[m]
__global__ __launch_bounds__(256) void out_reduce(const float* __restrict__ pbuf,
                                                  const float* __restrict__ dpart,
                                                  const float* __restrict__ u,
                                                  const float* __restrict__ X,
                                                  float* __restrict__ outP) {
    const int idx = blockIdx.x * 256 + threadIdx.x;   // per float4
    const int d4 = idx & (DD / 4 - 1);
    const int bm = idx >> 4;                           // b*NN + m
    float4 s = make_float4(0.f, 0.f, 0.f, 0.f);
    float denom = 0.f;
    #pragma unroll
    for (int nc = 0; nc < NC; ++nc) {
        float4 p = *(const float4*)(pbuf + (size_t)nc * BB * NN * DD
                                    + (size_t)bm * DD + d4 * 4);
        s.x += p.x; s.y += p.y; s.z += p.z; s.w += p.w;
        denom += dpart[(size_t)nc * BB * NN + bm];
    }
    const float um = KSCALE * u[bm];
    denom += um;
    float4 xx = *(const float4*)(X + (size_t)bm * DD + d4 * 4);
    s.x += um * xx.x; s.y += um * xx.y; s.z += um * xx.z; s.w += um * xx.w;
    const float inv = 1.0f / denom;
    *(float4*)(outP + (size_t)bm * DD + d4 * 4) =
        make_float4(inv * s.x, inv * s.y, inv * s.z, inv * s.w);
}

// ---------------------------------------------------------------- launch
extern "C" void kernel_launch(void* const* d_in, const int* in_sizes, int n_in,
                              void* d_out, int out_size, void* d_ws, size_t ws_size,
                              hipStream_t stream) {
    const float* X = (const float*)d_in[0];   // particles [B,N,D]
    const float* W = (const float*)d_in[1];   // weights   [B,N]
    float* outP = (float*)d_out;                       // [B,N,D]
    float* outW = outP + (size_t)BB * NN * DD;         // [B,N]

    float* ws = (float*)d_ws;
    const size_t nfloats = (size_t)BB * NN          // sq
                         + 16                       // scale
                         + 2 * (size_t)BB * NN      // u, v
                         + (size_t)BB * 32 * 64 + BB * 32   // pcol, ptot
                         + (size_t)NC * BB * NN * DD        // pbuf
                         + (size_t)BB * 32 * NN             // rsum
                         + (size_t)NC * BB * NN;            // dpart
    const size_t need = nfloats * 4
                      + (size_t)BB * NN * DD * 2    // Xbf
                      + (size_t)BB * DD * NN * 2    // Yt
                      + (size_t)BB * NN * NN;       // K fp8
    if (ws_size < need) return;

    float* sq    = ws;
    float* scale = sq + (size_t)BB * NN;
    float* u     = scale + 16;
    float* v     = u + (size_t)BB * NN;
    float* pcol  = v + (size_t)BB * NN;
    float* ptot  = pcol + (size_t)BB * 32 * 64;
    float* pbuf  = ptot + BB * 32;
    float* rsum  = pbuf + (size_t)NC * BB * NN * DD;
    float* dpart = rsum + (size_t)BB * 32 * NN;
    unsigned short* Xbf = (unsigned short*)(dpart + (size_t)NC * BB * NN);
    unsigned short* Yt  = Xbf + (size_t)BB * NN * DD;
    unsigned char*  K   = (unsigned char*)(Yt + (size_t)BB * DD * NN);

    stats1<<<dim3(BB * 32), 256, 0, stream>>>(X, Xbf, sq, pcol, ptot, outW);
    stats2<<<dim3(BB), 64, 0, stream>>>(pcol, ptot, scale);
    build_K<<<dim3(528 * BB), 256, 0, stream>>>(Xbf, sq, scale, K, rsum);
    ucombine<<<dim3(BB * NN / 256), 256, 0, stream>>>(rsum, W, u);   // u1 (v=1)
    for (int i = 0; i < ITERS - 1; ++i) {
        sink_pass<1><<<dim3(BB * NN / 8), 256, 0, stream>>>(K, u, W, v);  // v_i
        sink_pass<0><<<dim3(BB * NN / 8), 256, 0, stream>>>(K, v, W, u);  // u_{i+1}
    }
    yprep<<<dim3(BB * NN / 64), 256, 0, stream>>>(X, u, Yt);
    out_gemm<<<dim3((NN / 64) * NC * BB), 256, 0, stream>>>(K, Yt, u, pbuf, dpart);
    out_reduce<<<dim3(BB * NN * DD / 4 / 256), 256, 0, stream>>>(pbuf, dpart, u, X, outP);
}

// Round 10
// 164.536 us; speedup vs baseline: 4.0186x; 1.1245x over previous
//
#include <hip/hip_runtime.h>

#define BB 8
#define NN 2048
#define DD 64
#define NC 4            // split-K chunks for out_gemm
constexpr float EPS = 0.1f;
constexpr int ITERS = 10;
constexpr float KSCALE = 4096.0f;   // off-diag fp8 scale; diag handled analytically

typedef short bf16x8 __attribute__((ext_vector_type(8)));
typedef float f32x16 __attribute__((ext_vector_type(16)));
typedef float f32x2  __attribute__((ext_vector_type(2)));

// ---------------------------------------------------------------- fp8 helpers
__device__ inline float e4m3_to_f32_manual(unsigned int b) {
    unsigned int e = (b >> 3) & 15u, m = b & 7u;
    float v;
    if (e == 0) v = (float)m * 0.001953125f;              // m * 2^-9
    else        v = __uint_as_float(((e + 120u) << 23) | (m << 20));
    return (b & 0x80u) ? -v : v;
}

template <bool HI>
__device__ inline f32x2 cvt2_fp8(unsigned int w) {
#if __has_builtin(__builtin_amdgcn_cvt_pk_f32_fp8)
    return __builtin_amdgcn_cvt_pk_f32_fp8(w, HI);
#else
    f32x2 r; unsigned int s = HI ? (w >> 16) : w;
    r[0] = e4m3_to_f32_manual(s & 255u);
    r[1] = e4m3_to_f32_manual((s >> 8) & 255u);
    return r;
#endif
}

__device__ inline unsigned char f32_to_e4m3(float f) {   // f in [0, 448]
#if __has_builtin(__builtin_amdgcn_cvt_pk_fp8_f32)
    return (unsigned char)(__builtin_amdgcn_cvt_pk_fp8_f32(f, f, 0, false) & 0xFF);
#else
    if (!(f > 0.f)) return 0;
    if (f >= 448.f) return 0x7E;
    int e; float m = frexpf(f, &e);            // f = m*2^e, m in [0.5,1)
    if (e >= -5) {                              // normal: f >= 2^-6
        int mant = (int)roundf(m * 16.f) - 8;   // 0..8
        int ef = e + 6;
        if (mant == 8) { mant = 0; ef += 1; }
        if (ef >= 16) return 0x7E;
        return (unsigned char)((ef << 3) | mant);
    }
    int mant = (int)roundf(f * 512.f);          // subnormal
    if (mant >= 8) return 0x08;
    return (unsigned char)mant;
#endif
}

__device__ inline unsigned int pack4_e4m3(float a, float b, float c, float d) {
#if __has_builtin(__builtin_amdgcn_cvt_pk_fp8_f32)
    unsigned int w = 0;
    w = (unsigned int)__builtin_amdgcn_cvt_pk_fp8_f32(a, b, (int)w, false);
    w = (unsigned int)__builtin_amdgcn_cvt_pk_fp8_f32(c, d, (int)w, true);
    return w;
#else
    return (unsigned int)f32_to_e4m3(a) | ((unsigned int)f32_to_e4m3(b) << 8)
         | ((unsigned int)f32_to_e4m3(c) << 16) | ((unsigned int)f32_to_e4m3(d) << 24);
#endif
}

__device__ inline unsigned short f2bf_rne(float f) {
    unsigned int u = __float_as_uint(f);
    u += 0x7FFFu + ((u >> 16) & 1u);
    return (unsigned short)(u >> 16);
}

// ---------------------------------------------------------------- stats1
// Also initializes outW (folded former init_w launch).
__global__ __launch_bounds__(256) void stats1(const float* __restrict__ X,
                                              unsigned short* __restrict__ Xbf,
                                              float* __restrict__ sq,
                                              float* __restrict__ pcol,
                                              float* __restrict__ ptot,
                                              float* __restrict__ outW) {
    const int blk = blockIdx.x;          // 0 .. BB*32-1
    const int b   = blk & 7;
    const int ch  = blk >> 3;            // 0..31
    const int r0  = ch * 64;
    const int t = threadIdx.x, w = t >> 6, lane = t & 63;
    const int gidx = blk * 256 + t;
    if (gidx < BB * NN) outW[gidx] = 1.0f / (float)NN;
    const float* Xb = X + (size_t)b * NN * DD;
    unsigned short* Xbfb = Xbf + (size_t)b * NN * DD;
    float cs = 0.f, sqtot = 0.f;
    #pragma unroll
    for (int i = w; i < 64; i += 4) {
        const int row = r0 + i;
        float x = Xb[(size_t)row * DD + lane];
        unsigned short hb = f2bf_rne(x);
        Xbfb[(size_t)row * DD + lane] = hb;
        float xr = __uint_as_float((unsigned int)hb << 16);
        cs += xr;
        float s = xr * xr;
        #pragma unroll
        for (int off = 32; off > 0; off >>= 1) s += __shfl_down(s, off);
        if (lane == 0) { sq[b * NN + row] = s; sqtot += s; }
    }
    __shared__ float colS[4][64];
    __shared__ float totS[4];
    colS[w][lane] = cs;
    if (lane == 0) totS[w] = sqtot;
    __syncthreads();
    if (t < 64)
        pcol[(b * 32 + ch) * 64 + t] = colS[0][t] + colS[1][t] + colS[2][t] + colS[3][t];
    if (t == 0)
        ptot[b * 32 + ch] = totS[0] + totS[1] + totS[2] + totS[3];
}

// ---------------------------------------------------------------- stats2
__global__ void stats2(const float* __restrict__ pcol,
                       const float* __restrict__ ptot,
                       float* __restrict__ scale) {
    const int b = blockIdx.x, t = threadIdx.x;   // 64 threads
    float c = 0.f;
    #pragma unroll
    for (int p = 0; p < 32; ++p) c += pcol[(b * 32 + p) * 64 + t];
    float s2 = c * c;
    #pragma unroll
    for (int off = 32; off > 0; off >>= 1) s2 += __shfl_down(s2, off);
    if (t == 0) {
        float T = 0.f;
        #pragma unroll
        for (int p = 0; p < 32; ++p) T += ptot[b * 32 + p];
        float cmean = 2.0f * T / (float)NN
                    - 2.0f * s2 / ((float)NN * (float)NN) + 1e-8f;
        scale[b] = -1.0f / (cmean * EPS);
    }
}

// ---------------------------------------------------------------- build_K
// SYMMETRIC: one block per unordered tile pair (I<=J) per batch (528*8 blocks).
__global__ __launch_bounds__(256) void build_K(const unsigned short* __restrict__ Xbf,
                                               const float* __restrict__ sq,
                                               const float* __restrict__ scale,
                                               unsigned char* __restrict__ K,
                                               float* __restrict__ rsum) {
    __shared__ float T[64][68];
    const int bid = blockIdx.x;                   // 0..4223
    const int b = bid & 7;
    int q = bid >> 3, I = 0;                      // triangular decode (uniform)
    while (q >= 32 - I) { q -= 32 - I; ++I; }
    const int J = I + q;                          // I <= J
    const int t = threadIdx.x, w = t >> 6;
    const int lane = t & 63, l31 = lane & 31, lh = lane >> 5;
    const int wr = w >> 1, wc = w & 1;            // 32x32 quadrant of 64x64 tile
    const unsigned short* Xb = Xbf + (size_t)b * NN * DD;
    const int n_row = I * 64 + wr * 32 + l31;     // A: lane holds row l31 (I side)
    const int m_row = J * 64 + wc * 32 + l31;     // B: lane holds col l31 (J side)
    bf16x8 af[4], bf[4];
    #pragma unroll
    for (int s = 0; s < 4; ++s) {                 // k = s*16 + lh*8 + (0..7)
        af[s] = *(const bf16x8*)(Xb + (size_t)n_row * DD + s * 16 + lh * 8);
        bf[s] = *(const bf16x8*)(Xb + (size_t)m_row * DD + s * 16 + lh * 8);
    }
    f32x16 acc = {};
    #pragma unroll
    for (int s = 0; s < 4; ++s)
        acc = __builtin_amdgcn_mfma_f32_32x32x16_bf16(af[s], bf[s], acc, 0, 0, 0);
    // C/D: col = l31, row = (r&3) + 8*(r>>2) + 4*lh   [m74/m101 verified]
    const float sc = scale[b];
    const float* sqb = sq + b * NN;
    const int gm = J * 64 + wc * 32 + l31;
    const float sqm = sqb[gm];
    #pragma unroll
    for (int r = 0; r < 16; ++r) {
        const int row = (r & 3) + 8 * (r >> 2) + 4 * lh;
        const int gn = I * 64 + wr * 32 + row;
        float val = KSCALE * __expf(sc * (sqb[gn] + sqm - 2.0f * acc[r]));
        T[wr * 32 + row][wc * 32 + l31] = (gn == gm) ? 0.0f : val;
    }
    __syncthreads();
    unsigned char* Kb = K + (size_t)b * NN * NN;
    // ---- store 1: K[I-rows][J-cols], row-major from LDS, + row-sums
    {
        const int orow = t >> 2, oseg = t & 3;    // 64 rows x 4 segs of 16
        float vv[16];
        #pragma unroll
        for (int j = 0; j < 4; ++j)
            *(float4*)&vv[j * 4] = *(const float4*)&T[orow][oseg * 16 + j * 4];
        float rs = 0.f;
        #pragma unroll
        for (int j = 0; j < 16; ++j) rs += vv[j];
        rs += __shfl_down(rs, 2);
        rs += __shfl_down(rs, 1);
        if (oseg == 0)
            rsum[((size_t)b * 32 + J) * NN + I * 64 + orow] = rs;
        uint4 o;
        o.x = pack4_e4m3(vv[0],  vv[1],  vv[2],  vv[3]);
        o.y = pack4_e4m3(vv[4],  vv[5],  vv[6],  vv[7]);
        o.z = pack4_e4m3(vv[8],  vv[9],  vv[10], vv[11]);
        o.w = pack4_e4m3(vv[12], vv[13], vv[14], vv[15]);
        *(uint4*)(Kb + (size_t)(I * 64 + orow) * NN + J * 64 + oseg * 16) = o;
    }
    // ---- store 2 (I<J only): transpose tile -> K[J-rows][I-cols], + col-sums
    if (I != J) {
        const int c = t >> 2, rseg = t & 3;       // 64 cols x 4 segs of 16 rows
        float vv[16];
        #pragma unroll
        for (int j = 0; j < 16; ++j) vv[j] = T[rseg * 16 + j][c];
        float csum = 0.f;
        #pragma unroll
        for (int j = 0; j < 16; ++j) csum += vv[j];
        csum += __shfl_down(csum, 2);
        csum += __shfl_down(csum, 1);
        if (rseg == 0)
            rsum[((size_t)b * 32 + I) * NN + J * 64 + c] = csum;
        uint4 o;
        o.x = pack4_e4m3(vv[0],  vv[1],  vv[2],  vv[3]);
        o.y = pack4_e4m3(vv[4],  vv[5],  vv[6],  vv[7]);
        o.z = pack4_e4m3(vv[8],  vv[9],  vv[10], vv[11]);
        o.w = pack4_e4m3(vv[12], vv[13], vv[14], vv[15]);
        *(uint4*)(Kb + (size_t)(J * 64 + c) * NN + I * 64 + rseg * 16) = o;
    }
}

// ---------------------------------------------------------------- ucombine
// u1[b,n] = (w+1e-16) / ( sum_g rsum[b][g][n] + KSCALE )   (v=1 pass, free)
__global__ __launch_bounds__(256) void ucombine(const float* __restrict__ rsum,
                                                const float* __restrict__ W,
                                                float* __restrict__ u) {
    const int idx = blockIdx.x * 256 + threadIdx.x;   // 0..16383
    const int b = idx >> 11, n = idx & (NN - 1);
    float s = 0.f;
    #pragma unroll
    for (int g = 0; g < 32; ++g)
        s += rsum[((size_t)b * 32 + g) * NN + n];
    u[idx] = (W[idx] + 1e-16f) / (s + KSCALE);
}

// ---------------------------------------------------------------- sink_pass
// MODE 0: u[n] = (w[n]+1e-16) / ( sum_m K8[n,m]*v[m] + KSCALE*v[n] )
// MODE 1: v[m] = (1/N)        / ( sum_n K8[m,n]*u[n] + KSCALE*u[m] )
template <int MODE>
__global__ __launch_bounds__(256) void sink_pass(const unsigned char* __restrict__ K,
                                                 const float* __restrict__ vin,
                                                 const float* __restrict__ wts,
                                                 float* __restrict__ out) {
    __shared__ float vs[NN];
    const int bid = blockIdx.x;                   // 0..2047
    const int b = bid & 7, j = bid >> 3;          // j 0..255
    const int t = threadIdx.x, w = t >> 6, lane = t & 63;
    const float* vb = vin + (size_t)b * NN;
    #pragma unroll
    for (int s = 0; s < 2; ++s)
        *(float4*)&vs[(t + s * 256) * 4] = *(const float4*)&vb[(t + s * 256) * 4];
    __syncthreads();
    const int r0 = j * 8 + w * 2;                 // 2 rows per wave
    const unsigned char* Kr0 = K + ((size_t)b * NN + r0) * NN;
    const unsigned char* Kr1 = Kr0 + NN;
    float a0 = 0.f, a1 = 0.f;
    #pragma unroll
    for (int it = 0; it < 2; ++it) {
        const int m0 = it * 1024 + lane * 16;
        const uint4 ka = *(const uint4*)(Kr0 + m0);
        const uint4 kb = *(const uint4*)(Kr1 + m0);
        const float4 v0 = *(const float4*)&vs[m0];
        const float4 v1 = *(const float4*)&vs[m0 + 4];
        const float4 v2 = *(const float4*)&vs[m0 + 8];
        const float4 v3 = *(const float4*)&vs[m0 + 12];
        {
            f32x2 q0 = cvt2_fp8<false>(ka.x), q1 = cvt2_fp8<true>(ka.x);
            f32x2 q2 = cvt2_fp8<false>(ka.y), q3 = cvt2_fp8<true>(ka.y);
            f32x2 q4 = cvt2_fp8<false>(ka.z), q5 = cvt2_fp8<true>(ka.z);
            f32x2 q6 = cvt2_fp8<false>(ka.w), q7 = cvt2_fp8<true>(ka.w);
            a0 += q0[0]*v0.x + q0[1]*v0.y + q1[0]*v0.z + q1[1]*v0.w
                + q2[0]*v1.x + q2[1]*v1.y + q3[0]*v1.z + q3[1]*v1.w
                + q4[0]*v2.x + q4[1]*v2.y + q5[0]*v2.z + q5[1]*v2.w
                + q6[0]*v3.x + q6[1]*v3.y + q7[0]*v3.z + q7[1]*v3.w;
        }
        {
            f32x2 q0 = cvt2_fp8<false>(kb.x), q1 = cvt2_fp8<true>(kb.x);
            f32x2 q2 = cvt2_fp8<false>(kb.y), q3 = cvt2_fp8<true>(kb.y);
            f32x2 q4 = cvt2_fp8<false>(kb.z), q5 = cvt2_fp8<true>(kb.z);
            f32x2 q6 = cvt2_fp8<false>(kb.w), q7 = cvt2_fp8<true>(kb.w);
            a1 += q0[0]*v0.x + q0[1]*v0.y + q1[0]*v0.z + q1[1]*v0.w
                + q2[0]*v1.x + q2[1]*v1.y + q3[0]*v1.z + q3[1]*v1.w
                + q4[0]*v2.x + q4[1]*v2.y + q5[0]*v2.z + q5[1]*v2.w
                + q6[0]*v3.x + q6[1]*v3.y + q7[0]*v3.z + q7[1]*v3.w;
        }
    }
    #pragma unroll
    for (int off = 32; off > 0; off >>= 1) {
        a0 += __shfl_down(a0, off);
        a1 += __shfl_down(a1, off);
    }
    if (lane == 0) {
        const float n0 = (MODE == 0) ? (wts[(size_t)b*NN + r0] + 1e-16f) : (1.0f/(float)NN);
        const float n1 = (MODE == 0) ? (wts[(size_t)b*NN + r0 + 1] + 1e-16f) : (1.0f/(float)NN);
        out[(size_t)b * NN + r0]     = n0 / (a0 + KSCALE * vs[r0]);
        out[(size_t)b * NN + r0 + 1] = n1 / (a1 + KSCALE * vs[r0 + 1]);
    }
}

// ---------------------------------------------------------------- yprep
// Yt[b][d][n] = bf16( u[b][n] * X[b][n][d] )   (transposed for MFMA B-frags)
__global__ __launch_bounds__(256) void yprep(const float* __restrict__ X,
                                             const float* __restrict__ u,
                                             unsigned short* __restrict__ Yt) {
    __shared__ float T[64][65];
    const int bid = blockIdx.x;                   // 0..255
    const int b = bid & 7, nt = bid >> 3;
    const int t = threadIdx.x;
    const int nl = t >> 2, c0 = (t & 3) << 4;
    const float* Xb = X + ((size_t)b * NN + nt * 64) * DD;
    const float uu = u[(size_t)b * NN + nt * 64 + nl];
    #pragma unroll
    for (int j = 0; j < 4; ++j) {
        float4 x = *(const float4*)(Xb + (size_t)nl * DD + c0 + j * 4);
        T[c0 + j * 4 + 0][nl] = uu * x.x;
        T[c0 + j * 4 + 1][nl] = uu * x.y;
        T[c0 + j * 4 + 2][nl] = uu * x.z;
        T[c0 + j * 4 + 3][nl] = uu * x.w;
    }
    __syncthreads();
    const int d = t >> 2, n0 = (t & 3) << 4;
    unsigned short* Yr = Yt + ((size_t)b * DD + d) * NN + nt * 64 + n0;
    unsigned int ow[8];
    #pragma unroll
    for (int j = 0; j < 8; ++j) {
        unsigned int lo = f2bf_rne(T[d][n0 + 2 * j]);
        unsigned int hi = f2bf_rne(T[d][n0 + 2 * j + 1]);
        ow[j] = lo | (hi << 16);
    }
    *(uint4*)(Yr)     = make_uint4(ow[0], ow[1], ow[2], ow[3]);
    *(uint4*)(Yr + 8) = make_uint4(ow[4], ow[5], ow[6], ow[7]);
}

// ---------------------------------------------------------------- out_gemm
// pbuf[nc,b,m,d] = sum_{n in chunk} K8[m,n]*u[n]*x[n,d]  via bf16 MFMA.
// LDS-staged: K tile (64x128 fp8, pitch 136B) + Y tile (64x128 bf16, pitch
// 264B) loaded with coalesced 16B/lane; fragments read from LDS (2-way-free
// bank patterns). dpart side-channel fuses the final v-update.
#define KP 136
#define YP 264
__global__ __launch_bounds__(256) void out_gemm(const unsigned char* __restrict__ K,
                                                const unsigned short* __restrict__ Yt,
                                                const float* __restrict__ u,
                                                float* __restrict__ pbuf,
                                                float* __restrict__ dpart) {
    __shared__ __align__(16) unsigned char KsB[64 * KP];
    __shared__ __align__(16) unsigned char YsB[64 * YP];
    const int bid = blockIdx.x;                   // 0..1023
    const int b = bid & 7, tix = bid >> 3;        // tix 0..127
    const int nc = tix & (NC - 1), mt = tix >> 2; // mt 0..31
    const int t = threadIdx.x, w = t >> 6, lane = t & 63;
    const int l31 = lane & 31, lh = lane >> 5;
    const int wr = w >> 1, wc = w & 1;
    const unsigned char*  Kb = K + (size_t)b * NN * NN + (size_t)(mt * 64) * NN;
    const unsigned short* Yb = Yt + (size_t)b * DD * NN;
    const float* ub = u + (size_t)b * NN;
    f32x16 acc = {};
    float ds = 0.f;
    for (int st = 0; st < (NN / NC) / 128; ++st) {
        const int n0 = nc * (NN / NC) + st * 128;
        __syncthreads();
        #pragma unroll
        for (int i = 0; i < 2; ++i) {             // K tile: 64 rows x 128 B
            const int f = t + i * 256;            // 0..511
            const int row = f >> 3, seg = (f & 7) * 16;
            *(uint4*)(KsB + row * KP + seg) =
                *(const uint4*)(Kb + (size_t)row * NN + n0 + seg);
        }
        #pragma unroll
        for (int i = 0; i < 4; ++i) {             // Y tile: 64 rows x 128 bf16
            const int f = t + i * 256;            // 0..1023
            const int row = f >> 4, sege = (f & 15) * 8;
            *(uint4*)(YsB + row * YP + sege * 2) =
                *(const uint4*)(Yb + (size_t)row * NN + n0 + sege);
        }
        __syncthreads();
        #pragma unroll
        for (int kk = 0; kk < 8; ++kk) {
            const uint2 k8 = *(const uint2*)(KsB + (wr * 32 + l31) * KP
                                             + kk * 16 + lh * 8);
            f32x2 p0 = cvt2_fp8<false>(k8.x);
            f32x2 p1 = cvt2_fp8<true>(k8.x);
            f32x2 p2 = cvt2_fp8<false>(k8.y);
            f32x2 p3 = cvt2_fp8<true>(k8.y);
            if (wc == 0) {
                const int nu = n0 + kk * 16 + lh * 8;
                const float4 ua = *(const float4*)(ub + nu);
                const float4 uc = *(const float4*)(ub + nu + 4);
                ds += p0[0]*ua.x + p0[1]*ua.y + p1[0]*ua.z + p1[1]*ua.w
                    + p2[0]*uc.x + p2[1]*uc.y + p3[0]*uc.z + p3[1]*uc.w;
            }
            union { unsigned int u4[4]; bf16x8 v8; } av;
            av.u4[0] = __builtin_amdgcn_perm(__float_as_uint(p0[1]), __float_as_uint(p0[0]), 0x07060302);
            av.u4[1] = __builtin_amdgcn_perm(__float_as_uint(p1[1]), __float_as_uint(p1[0]), 0x07060302);
            av.u4[2] = __builtin_amdgcn_perm(__float_as_uint(p2[1]), __float_as_uint(p2[0]), 0x07060302);
            av.u4[3] = __builtin_amdgcn_perm(__float_as_uint(p3[1]), __float_as_uint(p3[0]), 0x07060302);
            const unsigned char* yb = YsB + (wc * 32 + l31) * YP
                                    + (kk * 16 + lh * 8) * 2;
            union { uint2 u2[2]; bf16x8 v8; } bv;
            bv.u2[0] = *(const uint2*)(yb);
            bv.u2[1] = *(const uint2*)(yb + 8);
            acc = __builtin_amdgcn_mfma_f32_32x32x16_bf16(av.v8, bv.v8, acc, 0, 0, 0);
        }
    }
    ds += __shfl_down(ds, 32);
    if (wc == 0 && lh == 0)
        dpart[((size_t)nc * BB + b) * NN + mt * 64 + wr * 32 + l31] = ds;
    float* pb = pbuf + (((size_t)nc * BB + b) * NN + mt * 64 + wr * 32) * DD
              + wc * 32 + l31;
    #pragma unroll
    for (int r = 0; r < 16; ++r) {
        const int row = (r & 3) + 8 * (r >> 2) + 4 * lh;
        pb[(size_t)row * DD] = acc[r];
    }
}

// ---------------------------------------------------------------- out_reduce
// denom[m] = sum_nc dpart + KSCALE*u[m]  (-> v10 = (1/N)/denom)
// out[b,m,d] = ( sum_nc pbuf + KSCALE*u[m]*x[m,d] ) / denom[m]
__global__ __launch_bounds__(256) void out_reduce(const float* __restrict__ pbuf,
                                                  const float* __restrict__ dpart,
                                                  const float* __restrict__ u,
                                                  const float* __restrict__ X,
                                                  float* __restrict__ outP) {
    const int idx = blockIdx.x * 256 + threadIdx.x;   // per float4
    const int d4 = idx & (DD / 4 - 1);
    const int bm = idx >> 4;                           // b*NN + m
    float4 s = make_float4(0.f, 0.f, 0.f, 0.f);
    float denom = 0.f;
    #pragma unroll
    for (int nc = 0; nc < NC; ++nc) {
        float4 p = *(const float4*)(pbuf + (size_t)nc * BB * NN * DD
                                    + (size_t)bm * DD + d4 * 4);
        s.x += p.x; s.y += p.y; s.z += p.z; s.w += p.w;
        denom += dpart[(size_t)nc * BB * NN + bm];
    }
    const float um = KSCALE * u[bm];
    denom += um;
    float4 xx = *(const float4*)(X + (size_t)bm * DD + d4 * 4);
    s.x += um * xx.x; s.y += um * xx.y; s.z += um * xx.z; s.w += um * xx.w;
    const float inv = 1.0f / denom;
    *(float4*)(outP + (size_t)bm * DD + d4 * 4) =
        make_float4(inv * s.x, inv * s.y, inv * s.z, inv * s.w);
}

// ---------------------------------------------------------------- launch
extern "C" void kernel_launch(void* const* d_in, const int* in_sizes, int n_in,
                              void* d_out, int out_size, void* d_ws, size_t ws_size,
                              hipStream_t stream) {
    const float* X = (const float*)d_in[0];   // particles [B,N,D]
    const float* W = (const float*)d_in[1];   // weights   [B,N]
    float* outP = (float*)d_out;                       // [B,N,D]
    float* outW = outP + (size_t)BB * NN * DD;         // [B,N]

    float* ws = (float*)d_ws;
    const size_t nfloats = (size_t)BB * NN          // sq
                         + 16                       // scale
                         + 2 * (size_t)BB * NN      // u, v
                         + (size_t)BB * 32 * 64 + BB * 32   // pcol, ptot
                         + (size_t)NC * BB * NN * DD        // pbuf
                         + (size_t)BB * 32 * NN             // rsum
                         + (size_t)NC * BB * NN;            // dpart
    const size_t need = nfloats * 4
                      + (size_t)BB * NN * DD * 2    // Xbf
                      + (size_t)BB * DD * NN * 2    // Yt
                      + (size_t)BB * NN * NN;       // K fp8
    if (ws_size < need) return;

    float* sq    = ws;
    float* scale = sq + (size_t)BB * NN;
    float* u     = scale + 16;
    float* v     = u + (size_t)BB * NN;
    float* pcol  = v + (size_t)BB * NN;
    float* ptot  = pcol + (size_t)BB * 32 * 64;
    float* pbuf  = ptot + BB * 32;
    float* rsum  = pbuf + (size_t)NC * BB * NN * DD;
    float* dpart = rsum + (size_t)BB * 32 * NN;
    unsigned short* Xbf = (unsigned short*)(dpart + (size_t)NC * BB * NN);
    unsigned short* Yt  = Xbf + (size_t)BB * NN * DD;
    unsigned char*  K   = (unsigned char*)(Yt + (size_t)BB * DD * NN);

    stats1<<<dim3(BB * 32), 256, 0, stream>>>(X, Xbf, sq, pcol, ptot, outW);
    stats2<<<dim3(BB), 64, 0, stream>>>(pcol, ptot, scale);
    build_K<<<dim3(528 * BB), 256, 0, stream>>>(Xbf, sq, scale, K, rsum);
    ucombine<<<dim3(BB * NN / 256), 256, 0, stream>>>(rsum, W, u);   // u1 (v=1)
    for (int i = 0; i < ITERS - 1; ++i) {
        sink_pass<1><<<dim3(BB * NN / 8), 256, 0, stream>>>(K, u, W, v);  // v_i
        sink_pass<0><<<dim3(BB * NN / 8), 256, 0, stream>>>(K, v, W, u);  // u_{i+1}
    }
    yprep<<<dim3(BB * NN / 64), 256, 0, stream>>>(X, u, Yt);
    out_gemm<<<dim3((NN / 64) * NC * BB), 256, 0, stream>>>(K, Yt, u, pbuf, dpart);
    out_reduce<<<dim3(BB * NN * DD / 4 / 256), 256, 0, stream>>>(pbuf, dpart, u, X, outP);
}